// Round 3
// baseline (870.294 us; speedup 1.0000x reference)
//
#include <hip/hip_runtime.h>
#include <math.h>

#define NFEAT 512
#define NHEADS 8
#define HDIM 64
#define NB 4
#define NG 1024
#define NC 1024
#define NQ 256
#define NEGV -9e15f
#define CHUNKS 16
#define FF ((size_t)NFEAT*NFEAT)
#define LSTR 36   // LDS row stride (ushorts) for reg-written P tiles only

typedef _Float16 v8h __attribute__((ext_vector_type(8)));
typedef float v4f __attribute__((ext_vector_type(4)));
#define MFMA16(a,b,c) __builtin_amdgcn_mfma_f32_16x16x32_f16((a),(b),(c),0,0,0)

// async global->LDS, 16B/lane, lane-linear LDS dest (wave-uniform base + lane*16)
#define GLDS(g, l) __builtin_amdgcn_global_load_lds( \
    (__attribute__((address_space(1))) void*)(g), \
    (__attribute__((address_space(3))) void*)(l), 16, 0, 0)

// XOR swizzle for 64B-row linear LDS tiles: physical 16B slot = quad ^ ((row>>1)&3).
__device__ __forceinline__ int ldsw(int row, int quad){
    return row*32 + (((quad) ^ ((row>>1)&3)) << 3);
}

__device__ __forceinline__ float lrelu(float x){ return fmaxf(x, 0.2f*x); }
__device__ __forceinline__ unsigned short f2h(float x){ union{_Float16 h; unsigned short u;} v; v.h = (_Float16)x; return v.u; }
__device__ __forceinline__ float h2f(unsigned short u){ union{_Float16 h; unsigned short u;} v; v.u = u; return (float)v.h; }

// ============ prep: fp32 -> fp16 flat ============
__global__ __launch_bounds__(256) void cvt_h_k(const float* __restrict__ src, unsigned short* __restrict__ dst){
    int idx = blockIdx.x*256 + threadIdx.x;
    const float4* s = (const float4*)(src + (size_t)idx*8);
    float4 a = s[0], b = s[1];
    ushort4 p0{f2h(a.x),f2h(a.y),f2h(a.z),f2h(a.w)};
    ushort4 p1{f2h(b.x),f2h(b.y),f2h(b.z),f2h(b.w)};
    *(ushort4*)(dst + (size_t)idx*8) = p0;
    *(ushort4*)(dst + (size_t)idx*8 + 4) = p1;
}

// ============ prep: fp32 -> fp16 hi/lo flat ============
__global__ __launch_bounds__(256) void cvt_hl_k(const float* __restrict__ src,
    unsigned short* __restrict__ dstHi, unsigned short* __restrict__ dstLo){
    int idx = blockIdx.x*256 + threadIdx.x;
    const float4* s = (const float4*)(src + (size_t)idx*8);
    float4 a = s[0], b = s[1];
    float x[8] = {a.x,a.y,a.z,a.w,b.x,b.y,b.z,b.w};
    unsigned short hi[8], lo[8];
    #pragma unroll
    for (int j = 0; j < 8; ++j){ hi[j] = f2h(x[j]); lo[j] = f2h(x[j] - h2f(hi[j])); }
    *(ushort4*)(dstHi + (size_t)idx*8)     = ushort4{hi[0],hi[1],hi[2],hi[3]};
    *(ushort4*)(dstHi + (size_t)idx*8 + 4) = ushort4{hi[4],hi[5],hi[6],hi[7]};
    *(ushort4*)(dstLo + (size_t)idx*8)     = ushort4{lo[0],lo[1],lo[2],lo[3]};
    *(ushort4*)(dstLo + (size_t)idx*8 + 4) = ushort4{lo[4],lo[5],lo[6],lo[7]};
}

// ============ prep: fusion weights -> transposed fp16 hi/lo, all 32 matrices ============
__global__ __launch_bounds__(256) void wtT_k(const float* __restrict__ w0, const float* __restrict__ w1,
    const float* __restrict__ w2, const float* __restrict__ w3,
    unsigned short* __restrict__ dstHi, unsigned short* __restrict__ dstLo){
    int bx = blockIdx.x;
    int mat = bx >> 6, t = bx & 63;
    int a = mat & 3, li = mat >> 2;
    const float* src = (a==0?w0:a==1?w1:a==2?w2:w3) + (size_t)li*FF;
    int fo0 = (t>>3)*64, fi0 = (t&7)*64;
    __shared__ float sT[64][65];
    int tid = threadIdx.x;
    #pragma unroll
    for (int it = 0; it < 4; ++it){
        int idx = it*256 + tid;
        int r = idx >> 4, c4 = idx & 15;
        float4 v = *(const float4*)(src + (size_t)(fi0+r)*512 + fo0 + c4*4);
        sT[r][c4*4+0]=v.x; sT[r][c4*4+1]=v.y; sT[r][c4*4+2]=v.z; sT[r][c4*4+3]=v.w;
    }
    __syncthreads();
    #pragma unroll
    for (int it = 0; it < 2; ++it){
        int idx = it*256 + tid;
        int dd = idx >> 3, c8 = idx & 7;
        unsigned short hi[8], lo[8];
        #pragma unroll
        for (int j = 0; j < 8; ++j){
            float x = sT[c8*8+j][dd];
            hi[j] = f2h(x);
            lo[j] = f2h(x - h2f(hi[j]));
        }
        size_t oo = (size_t)mat*FF + (size_t)(fo0+dd)*512 + fi0 + c8*8;
        *(ushort4*)(dstHi+oo)   = ushort4{hi[0],hi[1],hi[2],hi[3]};
        *(ushort4*)(dstHi+oo+4) = ushort4{hi[4],hi[5],hi[6],hi[7]};
        *(ushort4*)(dstLo+oo)   = ushort4{lo[0],lo[1],lo[2],lo[3]};
        *(ushort4*)(dstLo+oo+4) = ushort4{lo[4],lo[5],lo[6],lo[7]};
    }
}

// ============ prep: attention W repack (blocks 0..63) + wa vectors (blocks 64..79) ============
__global__ __launch_bounds__(256) void prep_attnW_k(const float* __restrict__ W,
    const float* __restrict__ a1, const float* __restrict__ a2,
    unsigned short* __restrict__ WT, float* __restrict__ wa1, float* __restrict__ wa2){
    int bx = blockIdx.x;
    int tid = threadIdx.x;
    if (bx >= 64){
        int idx = (bx - 64)*256 + tid;
        int h = idx >> 9;
        const float* Wp = W + (size_t)idx*64;
        float s1 = 0.f, s2 = 0.f;
        #pragma unroll
        for (int d = 0; d < 64; ++d){ float w = Wp[d]; s1 += w*a1[(h<<6)+d]; s2 += w*a2[(h<<6)+d]; }
        wa1[idx] = s1; wa2[idx] = s2;
        return;
    }
    int h = bx >> 3, f0 = (bx & 7)*64;
    __shared__ float sT[64][65];
    #pragma unroll
    for (int it = 0; it < 4; ++it){
        int idx = it*256 + tid;
        int r = idx >> 4, c4 = idx & 15;
        float4 v = *(const float4*)(W + ((size_t)h*512 + f0 + r)*64 + c4*4);
        sT[r][c4*4+0]=v.x; sT[r][c4*4+1]=v.y; sT[r][c4*4+2]=v.z; sT[r][c4*4+3]=v.w;
    }
    __syncthreads();
    #pragma unroll
    for (int it = 0; it < 2; ++it){
        int idx = it*256 + tid;
        int dd = idx >> 3, c8 = idx & 7;
        ushort4 p0{f2h(sT[c8*8+0][dd]),f2h(sT[c8*8+1][dd]),f2h(sT[c8*8+2][dd]),f2h(sT[c8*8+3][dd])};
        ushort4 p1{f2h(sT[c8*8+4][dd]),f2h(sT[c8*8+5][dd]),f2h(sT[c8*8+6][dd]),f2h(sT[c8*8+7][dd])};
        unsigned short* o = WT + ((size_t)h*64 + dd)*512 + f0 + c8*8;
        *(ushort4*)o = p0; *(ushort4*)(o+4) = p1;
    }
}

// ============ prep: adj_gc [b][g][c] int -> adjT fp16 [b][c][g] ============
__global__ __launch_bounds__(256) void adjT_h_k(const int* __restrict__ adj, unsigned short* __restrict__ dst){
    int b = blockIdx.z;
    int c0 = blockIdx.x*64, g0 = blockIdx.y*64;
    __shared__ int sI[64][65];
    int tid = threadIdx.x;
    #pragma unroll
    for (int it = 0; it < 4; ++it){
        int idx = it*256 + tid;
        int r = idx >> 4, c4 = idx & 15;
        int4 v = *(const int4*)(adj + ((size_t)b*NG + g0 + r)*NC + c0 + c4*4);
        sI[r][c4*4+0]=v.x; sI[r][c4*4+1]=v.y; sI[r][c4*4+2]=v.z; sI[r][c4*4+3]=v.w;
    }
    __syncthreads();
    #pragma unroll
    for (int it = 0; it < 2; ++it){
        int idx = it*256 + tid;
        int dd = idx >> 3, c8 = idx & 7;
        ushort4 p0, p1;
        #pragma unroll
        for (int j = 0; j < 4; ++j) (&p0.x)[j] = sI[c8*8+j][dd] > 0 ? (unsigned short)0x3C00 : (unsigned short)0;
        #pragma unroll
        for (int j = 0; j < 4; ++j) (&p1.x)[j] = sI[c8*8+4+j][dd] > 0 ? (unsigned short)0x3C00 : (unsigned short)0;
        unsigned short* o = dst + ((size_t)b*NC + c0 + dd)*NG + g0 + c8*8;
        *(ushort4*)o = p0; *(ushort4*)(o+4) = p1;
    }
}

// ============ prep: adj_gq [b][g][q] int -> adjT int [b][q][g] ============
__global__ __launch_bounds__(256) void adjT_int_k(const int* __restrict__ adj, int* __restrict__ dst){
    int b = blockIdx.z;
    int q0 = blockIdx.x*64, g0 = blockIdx.y*64;
    __shared__ int sI[64][65];
    int tid = threadIdx.x;
    #pragma unroll
    for (int it = 0; it < 4; ++it){
        int idx = it*256 + tid;
        int r = idx >> 4, c4 = idx & 15;
        int4 v = *(const int4*)(adj + ((size_t)b*NG + g0 + r)*NQ + q0 + c4*4);
        sI[r][c4*4+0]=v.x; sI[r][c4*4+1]=v.y; sI[r][c4*4+2]=v.z; sI[r][c4*4+3]=v.w;
    }
    __syncthreads();
    #pragma unroll
    for (int it = 0; it < 4; ++it){
        int idx = it*256 + tid;
        int dd = idx >> 4, c4 = idx & 15;
        int4 v{sI[c4*4+0][dd], sI[c4*4+1][dd], sI[c4*4+2][dd], sI[c4*4+3][dd]};
        *(int4*)(dst + ((size_t)b*NQ + q0 + dd)*NG + g0 + c4*4) = v;
    }
}

// ============ prep: fp32 act [b][rows][512] -> transposed hi/lo fp16 [b][512][rows] ============
__global__ __launch_bounds__(256) void actT_hl_k(const float* __restrict__ src,
    unsigned short* __restrict__ dstHi, unsigned short* __restrict__ dstLo, int Nrows){
    int b = blockIdx.z;
    int f0 = blockIdx.x*64, g0 = blockIdx.y*64;
    __shared__ float sF[64][65];
    int tid = threadIdx.x;
    #pragma unroll
    for (int it = 0; it < 4; ++it){
        int idx = it*256 + tid;
        int r = idx >> 4, c4 = idx & 15;
        float4 v = *(const float4*)(src + ((size_t)b*Nrows + g0 + r)*512 + f0 + c4*4);
        sF[r][c4*4+0]=v.x; sF[r][c4*4+1]=v.y; sF[r][c4*4+2]=v.z; sF[r][c4*4+3]=v.w;
    }
    __syncthreads();
    #pragma unroll
    for (int it = 0; it < 2; ++it){
        int idx = it*256 + tid;
        int dd = idx >> 3, c8 = idx & 7;
        unsigned short hi[8], lo[8];
        #pragma unroll
        for (int j = 0; j < 8; ++j){
            float x = sF[c8*8+j][dd];
            hi[j] = f2h(x);
            lo[j] = f2h(x - h2f(hi[j]));
        }
        size_t oo = ((size_t)b*512 + f0 + dd)*Nrows + g0 + c8*8;
        *(ushort4*)(dstHi+oo)   = ushort4{hi[0],hi[1],hi[2],hi[3]};
        *(ushort4*)(dstHi+oo+4) = ushort4{hi[4],hi[5],hi[6],hi[7]};
        *(ushort4*)(dstLo+oo)   = ushort4{lo[0],lo[1],lo[2],lo[3]};
        *(ushort4*)(dstLo+oo+4) = ushort4{lo[4],lo[5],lo[6],lo[7]};
    }
}

// ============ scores for q and kv in one launch ============
__global__ __launch_bounds__(256) void scores2_k(
    const unsigned short* __restrict__ qX, const float* __restrict__ wa1, float* __restrict__ qs, int nQblocks,
    const unsigned short* __restrict__ kX, const float* __restrict__ wa2, float* __restrict__ ks){
    int lane = threadIdx.x & 63;
    const unsigned short* X; const float* wa; float* sc; int row;
    if ((int)blockIdx.x < nQblocks){ X = qX; wa = wa1; sc = qs; row = blockIdx.x*4 + (threadIdx.x >> 6); }
    else { X = kX; wa = wa2; sc = ks; row = (blockIdx.x - nQblocks)*4 + (threadIdx.x >> 6); }
    const unsigned short* Xr = X + (size_t)row*NFEAT;
    float p[NHEADS];
    #pragma unroll
    for (int h = 0; h < NHEADS; ++h) p[h] = 0.f;
    #pragma unroll
    for (int c = 0; c < 8; ++c){
        float x = h2f(Xr[(c<<6) + lane]);
        #pragma unroll
        for (int h = 0; h < NHEADS; ++h) p[h] += x * wa[(h<<9) + (c<<6) + lane];
    }
    #pragma unroll
    for (int h = 0; h < NHEADS; ++h){
        float v = p[h];
        #pragma unroll
        for (int off = 32; off > 0; off >>= 1) v += __shfl_xor(v, off);
        if (lane == 0) sc[(size_t)row*NHEADS + h] = v;
    }
}

// ============ merged online colmax+colsum: per-chunk (cm, sum) in one adj pass ============
__global__ __launch_bounds__(256) void colstat_part_k(const int* __restrict__ adj, long bstride, int ns,
    const float* __restrict__ qs, const float* __restrict__ ks,
    float* __restrict__ pcm, float* __restrict__ psum, int N, int M){
    int b = blockIdx.z, ch = blockIdx.y;
    int ml = threadIdx.x & 63; int m = blockIdx.x*64 + ml;
    int g = threadIdx.x >> 6;
    int chunk = N / CHUNKS, subl = chunk >> 2;
    int n0 = ch*chunk + g*subl;
    const int* adjb = adj + (size_t)b*bstride;
    float ksv[8];
    size_t mo = ((size_t)b*M + m)*8;
    #pragma unroll
    for (int h = 0; h < 8; ++h) ksv[h] = ks[mo+h];
    float mx[8];
    #pragma unroll
    for (int h = 0; h < 8; ++h) mx[h] = -INFINITY;
    unsigned abits = 0;
    for (int i = 0; i < subl; ++i){
        int a = adjb[(size_t)(n0+i)*ns + m];
        const float* qr = qs + ((size_t)b*N + n0 + i)*8;
        if (a > 0){
            abits |= (1u << i);
            #pragma unroll
            for (int h = 0; h < 8; ++h) mx[h] = fmaxf(mx[h], qr[h]);
        }
    }
    float cm[8], s[8];
    #pragma unroll
    for (int h = 0; h < 8; ++h){
        cm[h] = abits ? lrelu(mx[h] + ksv[h]) : NEGV;
        s[h] = 0.f;
    }
    for (int i = 0; i < subl; ++i){
        bool on = (abits >> i) & 1;
        const float* qr = qs + ((size_t)b*N + n0 + i)*8;
        #pragma unroll
        for (int h = 0; h < 8; ++h){
            float e = on ? lrelu(qr[h] + ksv[h]) : NEGV;
            s[h] += __expf(e - cm[h]);
        }
    }
    __shared__ float scm[4][64][8], ssm[4][64][8];
    #pragma unroll
    for (int h = 0; h < 8; ++h){ scm[g][ml][h] = cm[h]; ssm[g][ml][h] = s[h]; }
    __syncthreads();
    if (g == 0){
        #pragma unroll
        for (int h = 0; h < 8; ++h){
            float c0 = scm[0][ml][h], c1 = scm[1][ml][h], c2 = scm[2][ml][h], c3 = scm[3][ml][h];
            float CM = fmaxf(fmaxf(c0, c1), fmaxf(c2, c3));
            float S = ssm[0][ml][h]*__expf(c0-CM) + ssm[1][ml][h]*__expf(c1-CM)
                    + ssm[2][ml][h]*__expf(c2-CM) + ssm[3][ml][h]*__expf(c3-CM);
            size_t o = (((size_t)b*CHUNKS + ch)*M + m)*8 + h;
            pcm[o] = CM; psum[o] = S;
        }
    }
}

// ============ merged finalize: chunk-combine + stat repack -> ksh/cmh/ish [b][8][M] ============
__global__ __launch_bounds__(256) void colfin_k(const float* __restrict__ pcm, const float* __restrict__ psum,
    const float* __restrict__ ks, float* __restrict__ ksh, float* __restrict__ cmh,
    float* __restrict__ ish, int M){
    int idx = blockIdx.x*256 + threadIdx.x;
    int m8 = M*8;
    int b = idx / m8, rem = idx - b*m8;
    int m = rem >> 3, h = rem & 7;
    size_t base = (size_t)b*CHUNKS*m8 + rem;
    float c[CHUNKS], s[CHUNKS];
    #pragma unroll
    for (int ch = 0; ch < CHUNKS; ++ch){
        c[ch] = pcm[base + (size_t)ch*m8];
        s[ch] = psum[base + (size_t)ch*m8];
    }
    float CM = c[0];
    #pragma unroll
    for (int ch = 1; ch < CHUNKS; ++ch) CM = fmaxf(CM, c[ch]);
    float S = 0.f;
    #pragma unroll
    for (int ch = 0; ch < CHUNKS; ++ch) S += s[ch]*__expf(c[ch] - CM);
    size_t o = ((size_t)b*8 + h)*M + m;
    ksh[o] = ks[idx]; cmh[o] = CM; ish[o] = 1.f/S;
}

// ============ fused fusion MFMA: 128x64 tile, 8 waves, double-buffered GLDS ============
// Grid 1D = 8*(rows/128)*NB, XCD-aware decode (T1). npass: 1 = hi only; 3 = hi/lo.
__global__ __launch_bounds__(512, 1) void fusion_all_k(
    const unsigned short* __restrict__ aHi, const unsigned short* __restrict__ aLo,
    const unsigned short* __restrict__ bHi, const unsigned short* __restrict__ bLo,
    const unsigned short* __restrict__ Whi, const unsigned short* __restrict__ Wlo,
    unsigned short* __restrict__ dst, unsigned short* __restrict__ dstLo,
    unsigned short* __restrict__ dstT, unsigned short* __restrict__ dstTLo,
    float* __restrict__ dstF, int rows, int npass){
    // T1: group the 8 c0-blocks of each (r0,b) panel onto one XCD.
    int nY = rows >> 7;                 // 128-row tiles
    int ppg = (nY * NB) >> 3;           // panels per XCD
    int F = blockIdx.x;
    int xcd = F & 7, t = F >> 3;
    int c0i = t / ppg;
    int p = xcd + ((t - c0i*ppg) << 3);
    int r0 = (p % nY) << 7, c0 = c0i << 6;
    int b = p / nY;
    int tid = threadIdx.x;
    // double-buffered: act tiles 128x32 (8KB each comp), weights 4 mats x 64x32 (16KB)
    __shared__ alignas(16) unsigned short aHs[2][4096], aLs[2][4096], bHs[2][4096], bLs[2][4096];
    __shared__ alignas(16) unsigned short wHs[2][8192], wLs[2][8192];
    size_t actOff = (size_t)b*rows*512;
    const unsigned short* aHG = aHi + actOff;
    const unsigned short* bHG = bHi + actOff;
    const unsigned short* aLG = aLo ? aLo + actOff : nullptr;
    const unsigned short* bLG = bLo ? bLo + actOff : nullptr;
    bool multi = (npass == 3);
    bool hasALo = multi && (aLG != nullptr);
    bool hasBLo = multi && (bLG != nullptr);
    int w = tid >> 6, lane = tid & 63;
    int wr = w >> 1, wc = w & 1;                  // 4x2 wave grid: 32x32 quadrant per wave
    int lrow = lane & 15, quad = lane >> 4;
    // staging: thread -> act row sr (0..127), logical slot sq (inverse-swizzled source)
    int sr = tid >> 2;
    int sq = (tid & 3) ^ ((sr >> 1) & 3);
    size_t aRow  = (size_t)(r0 + sr)*512 + sq*8;
    // weight staging: two 128-row calls over flattened [4*64][32]
    size_t wOff0 = ((size_t)(sr >> 6)*512 + c0 + (sr & 63))*512 + sq*8;
    size_t wOff1 = ((size_t)((sr + 128) >> 6)*512 + c0 + ((sr + 128) & 63))*512 + sq*8;
    int aD  = w << 9;            // per-wave LDS dest (shorts)
    int wD1 = 4096 + (w << 9);
    v4f accN[2][2], accF[2][2];
    #pragma unroll
    for (int r = 0; r < 2; ++r)
        #pragma unroll
        for (int cf = 0; cf < 2; ++cf){ accN[r][cf] = (v4f)0.f; accF[r][cf] = (v4f)0.f; }

    #define FSTAGE(bb, kk) do{ \
        GLDS(aHG + aRow + (kk), &aHs[bb][aD]); \
        GLDS(bHG + aRow + (kk), &bHs[bb][aD]); \
        if (hasALo) GLDS(aLG + aRow + (kk), &aLs[bb][aD]); \
        if (hasBLo) GLDS(bLG + aRow + (kk), &bLs[bb][aD]); \
        GLDS(Whi + wOff0 + (kk), &wHs[bb][aD]); \
        GLDS(Whi + wOff1 + (kk), &wHs[bb][wD1]); \
        if (multi){ \
            GLDS(Wlo + wOff0 + (kk), &wLs[bb][aD]); \
            GLDS(Wlo + wOff1 + (kk), &wLs[bb][wD1]); \
        } \
    } while(0)

    FSTAGE(0, 0);
    __syncthreads();
    int buf = 0;
    for (int kt = 0; kt < 512; kt += 32){
        int ktn = kt + 32;
        if (ktn < 512) FSTAGE(buf^1, ktn);
        v8h ah[2], bh[2], al[2], bl[2];
        #pragma unroll
        for (int r = 0; r < 2; ++r){
            int ao = ldsw(wr*32 + r*16 + lrow, quad);
            ah[r] = *(const v8h*)&aHs[buf][ao];
            bh[r] = *(const v8h*)&bHs[buf][ao];
            if (hasALo) al[r] = *(const v8h*)&aLs[buf][ao];
            if (hasBLo) bl[r] = *(const v8h*)&bLs[buf][ao];
        }
        #pragma unroll
        for (int cf = 0; cf < 2; ++cf){
            int wo = ldsw(wc*32 + cf*16 + lrow, quad);
            v8h w0 = *(const v8h*)&wHs[buf][wo];
            v8h w1 = *(const v8h*)&wHs[buf][2048 + wo];
            v8h w2 = *(const v8h*)&wHs[buf][4096 + wo];
            v8h w3 = *(const v8h*)&wHs[buf][6144 + wo];
            v8h l0, l1, l2, l3;
            if (multi){
                l0 = *(const v8h*)&wLs[buf][wo];
                l1 = *(const v8h*)&wLs[buf][2048 + wo];
                l2 = *(const v8h*)&wLs[buf][4096 + wo];
                l3 = *(const v8h*)&wLs[buf][6144 + wo];
            }
            #pragma unroll
            for (int r = 0; r < 2; ++r){
                accN[r][cf] = MFMA16(ah[r], w0, accN[r][cf]);
                accN[r][cf] = MFMA16(bh[r], w1, accN[r][cf]);
                accF[r][cf] = MFMA16(ah[r], w2, accF[r][cf]);
                accF[r][cf] = MFMA16(bh[r], w3, accF[r][cf]);
                if (multi){
                    if (hasALo){ accN[r][cf] = MFMA16(al[r], w0, accN[r][cf]); accF[r][cf] = MFMA16(al[r], w2, accF[r][cf]); }
                    if (hasBLo){ accN[r][cf] = MFMA16(bl[r], w1, accN[r][cf]); accF[r][cf] = MFMA16(bl[r], w3, accF[r][cf]); }
                    accN[r][cf] = MFMA16(ah[r], l0, accN[r][cf]);
                    accN[r][cf] = MFMA16(bh[r], l1, accN[r][cf]);
                    accF[r][cf] = MFMA16(ah[r], l2, accF[r][cf]);
                    accF[r][cf] = MFMA16(bh[r], l3, accF[r][cf]);
                }
            }
        }
        __syncthreads();
        buf ^= 1;
    }
    #undef FSTAGE
    #pragma unroll
    for (int r = 0; r < 2; ++r)
        #pragma unroll
        for (int cf = 0; cf < 2; ++cf){
            int colg = c0 + wc*32 + cf*16 + lrow;
            int rbase = r0 + wr*32 + r*16 + quad*4;
            float o4[4];
            #pragma unroll
            for (int reg = 0; reg < 4; ++reg){
                float f = 1.f/(1.f + __expf(-accF[r][cf][reg]));
                size_t ai = (size_t)(rbase+reg)*512 + colg;
                float ao = h2f(aHG[ai]);
                if (aLG) ao += h2f(aLG[ai]);
                o4[reg] = f*accN[r][cf][reg] + (1.f - f)*ao;
                size_t oo = ((size_t)b*rows + rbase + reg)*512 + colg;
                unsigned short hv = f2h(o4[reg]);
                dst[oo] = hv;
                if (dstLo) dstLo[oo] = f2h(o4[reg] - h2f(hv));
                if (dstF) dstF[oo] = o4[reg];
            }
            if (dstT){
                unsigned short h0 = f2h(o4[0]), h1 = f2h(o4[1]), h2 = f2h(o4[2]), h3 = f2h(o4[3]);
                size_t to = ((size_t)b*512 + colg)*rows + rbase;
                *(ushort4*)&dstT[to] = ushort4{h0,h1,h2,h3};
                if (dstTLo)
                    *(ushort4*)&dstTLo[to] = ushort4{f2h(o4[0]-h2f(h0)), f2h(o4[1]-h2f(h1)),
                                                     f2h(o4[2]-h2f(h2)), f2h(o4[3]-h2f(h3))};
            }
        }
}

// ============ generic MFMA GEMM (64-row tiles, double-buffered): C[b] = A[b]@BT^T (+ A[b]@BT2^T) ============
__global__ __launch_bounds__(256) void gemmT_mfma_k(
    const unsigned short* __restrict__ A, size_t aStride,
    const unsigned short* __restrict__ BT, const unsigned short* __restrict__ BT2, size_t bStride,
    int K, int rowsPB,
    unsigned short* __restrict__ outRM, unsigned short* __restrict__ outLo,
    unsigned short* __restrict__ outT){
    int b = blockIdx.z;
    int r0 = blockIdx.y*64, c0 = blockIdx.x*64;
    int tid = threadIdx.x;
    __shared__ alignas(16) unsigned short aS[2][2048], bS[2][2048];
    const unsigned short* aG = A + (size_t)b*aStride;
    const unsigned short* bG0 = BT + (size_t)b*bStride;
    const unsigned short* bG1 = BT2 ? BT2 + (size_t)b*bStride : nullptr;
    int w = tid >> 6, lane = tid & 63;
    int lrow = lane & 15, quad = lane >> 4;
    int sr = tid >> 2;
    int sq = (tid & 3) ^ ((sr >> 1) & 3);
    size_t aRow = (size_t)(r0 + sr)*K + sq*8;
    size_t bRow = (size_t)(c0 + sr)*K + sq*8;
    int spp = K >> 5;
    int nsteps = (BT2 ? 2 : 1)*spp;
    v4f acc[4];
    #pragma unroll
    for (int cf = 0; cf < 4; ++cf) acc[cf] = (v4f)0.f;
    GLDS(aG + aRow, &aS[0][w << 9]);
    GLDS(bG0 + bRow, &bS[0][w << 9]);
    __syncthreads();
    int buf = 0;
    for (int s = 0; s < nsteps; ++s){
        int sn = s + 1;
        if (sn < nsteps){
            int ktn = ((sn >= spp) ? (sn - spp) : sn) << 5;
            const unsigned short* bgn = (sn >= spp) ? bG1 : bG0;
            GLDS(aG + aRow + ktn, &aS[buf^1][w << 9]);
            GLDS(bgn + bRow + ktn, &bS[buf^1][w << 9]);
        }
        v8h af = *(const v8h*)&aS[buf][ldsw(w*16 + lrow, quad)];
        #pragma unroll
        for (int cf = 0; cf < 4; ++cf){
            v8h bf = *(const v8h*)&bS[buf][ldsw(cf*16 + lrow, quad)];
            acc[cf] = MFMA16(af, bf, acc[cf]);
        }
        __syncthreads();
        buf ^= 1;
    }
    #pragma unroll
    for (int cf = 0; cf < 4; ++cf){
        int colg = c0 + cf*16 + lrow;
        int rbase = r0 + w*16 + quad*4;
        if (outRM){
            #pragma unroll
            for (int reg = 0; reg < 4; ++reg){
                float v = acc[cf][reg];
                unsigned short hv = f2h(v);
                size_t oo = ((size_t)b*rowsPB + rbase + reg)*512 + colg;
                outRM[oo] = hv;
                if (outLo) outLo[oo] = f2h(v - h2f(hv));
            }
        }
        if (outT){
            ushort4 pk{f2h(acc[cf][0]), f2h(acc[cf][1]), f2h(acc[cf][2]), f2h(acc[cf][3])};
            *(ushort4*)&outT[((size_t)b*512 + colg)*rowsPB + rbase] = pk;
        }
    }
}

// ============ attention output MFMA: double-buffered, 1 barrier / 32-chunk, reg prefetch ============
__global__ __launch_bounds__(256) void attn_mfma_k(const int* __restrict__ adj, long bstride, int ns,
    const float* __restrict__ qs, const float* __restrict__ ksh, const float* __restrict__ cmh,
    const float* __restrict__ ish, const unsigned short* __restrict__ WkT,
    unsigned short* __restrict__ outp, int N, int M){
    int bh = blockIdx.y; int b = bh >> 3, h = bh & 7;
    int n0 = blockIdx.x*64;
    int tid = threadIdx.x;
    __shared__ unsigned short pS[2*64*LSTR];
    __shared__ alignas(16) unsigned short wS[2*2048];
    __shared__ float qsS[64];
    if (tid < 64) qsS[tid] = qs[((size_t)b*N + n0 + tid)*8 + h];
    const int* adjb = adj + (size_t)b*bstride;
    const float* ksb = ksh + ((size_t)b*8 + h)*M;
    const float* cmb = cmh + ((size_t)b*8 + h)*M;
    const float* isb = ish + ((size_t)b*8 + h)*M;
    const unsigned short* wkb = WkT + ((size_t)b*512 + h*64)*M;
    int w = tid >> 6, lane = tid & 63;
    int lrow = lane & 15, quad = lane >> 4;
    int pn = tid >> 2, pm = (tid & 3)*8;
    int sr = tid >> 2;
    int sq = (tid & 3) ^ ((sr >> 1) & 3);
    const int* arowb = adjb + (size_t)(n0+pn)*ns + pm;
    v4f acc[4];
    #pragma unroll
    for (int cf = 0; cf < 4; ++cf) acc[cf] = (v4f)0.f;
    // preload chunk 0 into reg set A
    int4 A0 = *(const int4*)(arowb);
    int4 A1 = *(const int4*)(arowb + 4);
    float4 K0 = *(const float4*)(ksb + pm), K1 = *(const float4*)(ksb + pm + 4);
    float4 C0 = *(const float4*)(cmb + pm), C1 = *(const float4*)(cmb + pm + 4);
    float4 I0 = *(const float4*)(isb + pm), I1 = *(const float4*)(isb + pm + 4);
    int4 B0, B1; float4 LK0, LK1, LC0, LC1, LI0, LI1;
    __syncthreads();          // qsS visible
    float qv = qsS[pn];
    for (int mt = 0; mt < M; mt += 64){
        int mtB = mt + 32;
        int mtN = (mt + 64 < M) ? (mt + 64) : 0;
        // ---- sub-step 0: buf0, compute from A, prefetch B(mtB) ----
        GLDS(wkb + (size_t)sr*M + mt + sq*8, &wS[w << 9]);
        B0 = *(const int4*)(arowb + mtB); B1 = *(const int4*)(arowb + mtB + 4);
        LK0 = *(const float4*)(ksb + mtB + pm); LK1 = *(const float4*)(ksb + mtB + pm + 4);
        LC0 = *(const float4*)(cmb + mtB + pm); LC1 = *(const float4*)(cmb + mtB + pm + 4);
        LI0 = *(const float4*)(isb + mtB + pm); LI1 = *(const float4*)(isb + mtB + pm + 4);
        {
            float p[8];
            const int* aa0 = &A0.x; const int* aa1 = &A1.x;
            const float* kk0 = &K0.x; const float* kk1 = &K1.x;
            const float* cc0 = &C0.x; const float* cc1 = &C1.x;
            const float* ii0 = &I0.x; const float* ii1 = &I1.x;
            #pragma unroll
            for (int j = 0; j < 4; ++j){
                float e = (aa0[j] > 0) ? lrelu(qv + kk0[j]) : NEGV;
                p[j] = __expf(e - cc0[j]) * ii0[j];
            }
            #pragma unroll
            for (int j = 0; j < 4; ++j){
                float e = (aa1[j] > 0) ? lrelu(qv + kk1[j]) : NEGV;
                p[4+j] = __expf(e - cc1[j]) * ii1[j];
            }
            *(ushort4*)&pS[pn*LSTR + pm]     = ushort4{f2h(p[0]), f2h(p[1]), f2h(p[2]), f2h(p[3])};
            *(ushort4*)&pS[pn*LSTR + pm + 4] = ushort4{f2h(p[4]), f2h(p[5]), f2h(p[6]), f2h(p[7])};
        }
        __syncthreads();
        {
            v8h af = *(const v8h*)&pS[(w*16 + lrow)*LSTR + quad*8];
            #pragma unroll
            for (int cf = 0; cf < 4; ++cf){
                v8h bf = *(const v8h*)&wS[ldsw(cf*16 + lrow, quad)];
                acc[cf] = MFMA16(af, bf, acc[cf]);
            }
        }
        // ---- sub-step 1: buf1, compute from B, prefetch A(mtN) ----
        GLDS(wkb + (size_t)sr*M + mtB + sq*8, &wS[2048 + (w << 9)]);
        A0 = *(const int4*)(arowb + mtN); A1 = *(const int4*)(arowb + mtN + 4);
        K0 = *(const float4*)(ksb + mtN + pm); K1 = *(const float4*)(ksb + mtN + pm + 4);
        C0 = *(const float4*)(cmb + mtN + pm); C1 = *(const float4*)(cmb + mtN + pm + 4);
        I0 = *(const float4*)(isb + mtN + pm); I1 = *(const float4*)(isb + mtN + pm + 4);
        {
            float p[8];
            const int* aa0 = &B0.x; const int* aa1 = &B1.x;
            const float* kk0 = &LK0.x; const float* kk1 = &LK1.x;
            const float* cc0 = &LC0.x; const float* cc1 = &LC1.x;
            const float* ii0 = &LI0.x; const float* ii1 = &LI1.x;
            #pragma unroll
            for (int j = 0; j < 4; ++j){
                float e = (aa0[j] > 0) ? lrelu(qv + kk0[j]) : NEGV;
                p[j] = __expf(e - cc0[j]) * ii0[j];
            }
            #pragma unroll
            for (int j = 0; j < 4; ++j){
                float e = (aa1[j] > 0) ? lrelu(qv + kk1[j]) : NEGV;
                p[4+j] = __expf(e - cc1[j]) * ii1[j];
            }
            *(ushort4*)&pS[2304 + pn*LSTR + pm]     = ushort4{f2h(p[0]), f2h(p[1]), f2h(p[2]), f2h(p[3])};
            *(ushort4*)&pS[2304 + pn*LSTR + pm + 4] = ushort4{f2h(p[4]), f2h(p[5]), f2h(p[6]), f2h(p[7])};
        }
        __syncthreads();
        {
            v8h af = *(const v8h*)&pS[2304 + (w*16 + lrow)*LSTR + quad*8];
            #pragma unroll
            for (int cf = 0; cf < 4; ++cf){
                v8h bf = *(const v8h*)&wS[2048 + ldsw(cf*16 + lrow, quad)];
                acc[cf] = MFMA16(af, bf, acc[cf]);
            }
        }
    }
    #pragma unroll
    for (int cf = 0; cf < 4; ++cf){
        int colg = h*64 + cf*16 + lrow;
        int rbase = n0 + w*16 + quad*4;
        #pragma unroll
        for (int reg = 0; reg < 4; ++reg){
            float v = acc[cf][reg];
            v = (v > 0.f) ? v : (__expf(v) - 1.f);
            outp[((size_t)b*N + rbase + reg)*512 + colg] = f2h(v);
        }
    }
}

extern "C" void kernel_launch(void* const* d_in, const int* in_sizes, int n_in,
                              void* d_out, int out_size, void* d_ws, size_t ws_size,
                              hipStream_t stream){
    const float* in_gloss = (const float*)d_in[0];
    const float* in_clip  = (const float*)d_in[1];
    const float* in_q     = (const float*)d_in[2];
    const int*   adj_gc   = (const int*)d_in[3];
    const int*   adj_gq   = (const int*)d_in[4];
    const float* c2gW  = (const float*)d_in[5];
    const float* c2ga1 = (const float*)d_in[6];
    const float* c2ga2 = (const float*)d_in[7];
    const float* g2qW  = (const float*)d_in[8];
    const float* g2qa1 = (const float*)d_in[9];
    const float* g2qa2 = (const float*)d_in[10];
    const float* q2gW  = (const float*)d_in[11];
    const float* q2ga1 = (const float*)d_in[12];
    const float* q2ga2 = (const float*)d_in[13];
    const float* fusW  = (const float*)d_in[14];
    const float* fusU  = (const float*)d_in[15];
    const float* fusWf = (const float*)d_in[16];
    const float* fusUf = (const float*)d_in[17];
    float* out = (float*)d_out;
    float* out_gloss = out;
    float* out_clip  = out + (size_t)NB*NG*NFEAT;
    float* out_q     = out + (size_t)NB*NG*NFEAT*2;

    char* wsB = (char*)d_ws;
    size_t off = 0;
    auto alloc = [&](size_t bytes){ void* p = wsB + off; off += (bytes + 255) & ~(size_t)255; return p; };
    float* wa1   = (float*)alloc(4096*4);
    float* wa2   = (float*)alloc(4096*4);
    float* qsb   = (float*)alloc((size_t)NB*NG*8*4);
    float* ksb   = (float*)alloc((size_t)NB*NG*8*4);
    float* ksh   = (float*)alloc((size_t)NB*NG*8*4);
    float* cmh   = (float*)alloc((size_t)NB*NG*8*4);
    float* ish   = (float*)alloc((size_t)NB*NG*8*4);
    float* pmaxb = (float*)alloc((size_t)NB*CHUNKS*NG*8*4);
    float* psumb = (float*)alloc((size_t)NB*CHUNKS*NG*8*4);
    unsigned short* WflatT  = (unsigned short*)alloc((size_t)NFEAT*NFEAT*2);
    unsigned short* wtAll   = (unsigned short*)alloc((size_t)32*FF*2);
    unsigned short* wtAllLo = (unsigned short*)alloc((size_t)32*FF*2);
    unsigned short* adjTgc  = (unsigned short*)alloc((size_t)NB*NC*NG*2);
    unsigned short* g_bf0   = (unsigned short*)alloc((size_t)NB*NG*NFEAT*2);
    unsigned short* gLo0    = (unsigned short*)alloc((size_t)NB*NG*NFEAT*2);
    unsigned short* g_bf1   = (unsigned short*)alloc((size_t)NB*NG*NFEAT*2);
    unsigned short* gLo1    = (unsigned short*)alloc((size_t)NB*NG*NFEAT*2);
    unsigned short* gT      = (unsigned short*)alloc((size_t)NB*NFEAT*NG*2);
    unsigned short* gTlo    = (unsigned short*)alloc((size_t)NB*NFEAT*NG*2);
    unsigned short* gA_bf   = (unsigned short*)alloc((size_t)NB*NG*NFEAT*2);
    unsigned short* gALo    = (unsigned short*)alloc((size_t)NB*NG*NFEAT*2);
    unsigned short* c_bf0   = (unsigned short*)alloc((size_t)NB*NC*NFEAT*2);
    unsigned short* cLo0    = (unsigned short*)alloc((size_t)NB*NC*NFEAT*2);
    unsigned short* c_bf1   = (unsigned short*)alloc((size_t)NB*NC*NFEAT*2);
    unsigned short* cLo1    = (unsigned short*)alloc((size_t)NB*NC*NFEAT*2);
    unsigned short* q_bf0   = (unsigned short*)alloc((size_t)NB*NQ*NFEAT*2);
    unsigned short* q_bf1   = (unsigned short*)alloc((size_t)NB*NQ*NFEAT*2);
    unsigned short* agg_bf  = (unsigned short*)alloc((size_t)NB*NG*NFEAT*2);
    unsigned short* aggLo   = (unsigned short*)alloc((size_t)NB*NG*NFEAT*2);
    unsigned short* WkT     = (unsigned short*)alloc((size_t)NB*NFEAT*NG*2);
    int* adjTgq = (int*)alloc((size_t)NB*NQ*NG*4);
    (void)ws_size; (void)in_sizes; (void)n_in; (void)out_size;

    const size_t HFD = (size_t)NHEADS*NFEAT*HDIM;
    const size_t HD  = (size_t)NHEADS*HDIM;

    // ---- prep ----
    wtT_k<<<2048, 256, 0, stream>>>(fusW, fusU, fusWf, fusUf, wtAll, wtAllLo);
    adjT_h_k<<<dim3(NC/64, NG/64, NB), 256, 0, stream>>>(adj_gc, adjTgc);
    adjT_int_k<<<dim3(NQ/64, NG/64, NB), 256, 0, stream>>>(adj_gq, adjTgq);
    cvt_hl_k<<<(NB*NG*NFEAT)/2048, 256, 0, stream>>>(in_gloss, g_bf0, gLo0);
    cvt_hl_k<<<(NB*NC*NFEAT)/2048, 256, 0, stream>>>(in_clip,  c_bf0, cLo0);
    cvt_h_k<<<(NB*NQ*NFEAT)/2048, 256, 0, stream>>>(in_q,     q_bf0);
    actT_hl_k<<<dim3(8, NG/64, NB), 256, 0, stream>>>(in_gloss, gT, gTlo, NG);

    auto run_attn = [&](const unsigned short* qX, int N, const unsigned short* kvX, int M,
                        const int* adjp, long bstride, int ns,
                        const float* W, const float* a1, const float* a2, unsigned short* dst){
        prep_attnW_k<<<80, 256, 0, stream>>>(W, a1, a2, WflatT, wa1, wa2);
        scores2_k<<<(NB*(N+M))/4, 256, 0, stream>>>(qX, wa1, qsb, (NB*N)/4, kvX, wa2, ksb);
        gemmT_mfma_k<<<dim3(8, M/64, NB), 256, 0, stream>>>(kvX, (size_t)M*512, WflatT, nullptr, 0,
                                                            512, M, nullptr, nullptr, WkT);
        colstat_part_k<<<dim3(M/64, CHUNKS, NB), 256, 0, stream>>>(adjp, bstride, ns, qsb, ksb,
                                                                   pmaxb, psumb, N, M);
        colfin_k<<<(NB*M*8)/256, 256, 0, stream>>>(pmaxb, psumb, ksb, ksh, cmh, ish, M);
        attn_mfma_k<<<dim3(N/64, NB*8), 256, 0, stream>>>(adjp, bstride, ns, qsb, ksh, cmh, ish,
                                                          WkT, dst, N, M);
    };
    auto run_fusion = [&](const unsigned short* a, const unsigned short* aLo,
                          const unsigned short* bb, const unsigned short* bLo, int rows,
                          int l, int i, int npass,
                          unsigned short* dst, unsigned short* dstLo,
                          unsigned short* dstT, unsigned short* dstTLo, float* dstF){
        const unsigned short* Whi = wtAll   + (size_t)((l*4 + i)*4)*FF;
        const unsigned short* Wlo = wtAllLo + (size_t)((l*4 + i)*4)*FF;
        fusion_all_k<<<dim3(8*(rows/128)*NB), 512, 0, stream>>>(
            a, aLo, bb, bLo, Whi, Wlo, dst, dstLo, dstT, dstTLo, dstF, rows, npass);
    };

    for (int l = 0; l < 2; ++l){
        const unsigned short* g_cur = (l == 0) ? g_bf0 : g_bf1;
        const unsigned short* gLoC  = (l == 0) ? gLo0  : gLo1;
        const unsigned short* c_cur = (l == 0) ? c_bf0 : c_bf1;
        const unsigned short* cLoC  = (l == 0) ? cLo0  : cLo1;
        const unsigned short* q_cur = (l == 0) ? q_bf0 : q_bf1;
        unsigned short* g_nxt = (l == 0) ? g_bf1 : g_bf0;
        unsigned short* gLoN  = (l == 0) ? gLo1  : nullptr;
        unsigned short* c_nxt = (l == 0) ? c_bf1 : c_bf0;
        unsigned short* cLoN  = (l == 0) ? cLo1  : nullptr;
        unsigned short* q_nxt = (l == 0) ? q_bf1 : q_bf0;
        float* gF = (l == 1) ? out_gloss : nullptr;
        float* cF = (l == 1) ? out_clip  : nullptr;
        float* qF = (l == 1) ? out_q     : nullptr;

        // gloss_same = adj_gc^T @ gloss  (hi/lo B, hi/lo out)
        gemmT_mfma_k<<<dim3(8, NC/64, NB), 256, 0, stream>>>(adjTgc, (size_t)NC*NG, gT, gTlo,
                                                             (size_t)512*NG, NG, NC,
                                                             agg_bf, aggLo, nullptr);
        // clip_1 (3-pass hi/lo)
        run_fusion(c_cur, cLoC, agg_bf, aggLo, NC, l, 0, 3,
                   c_nxt, cLoN, nullptr, nullptr, cF);
        // clip_agg = attn(q=gloss, kv=clip, adj_gc)
        run_attn(g_cur, NG, c_cur, NC, adj_gc, (long)NG*NC, NC,
                 c2gW + l*HFD, c2ga1 + l*HD, c2ga2 + l*HD, agg_bf);
        // gloss_1 (single pass; aLo still used for exact gate residual)
        run_fusion(g_cur, gLoC, agg_bf, nullptr, NG, l, 1, 1,
                   gA_bf, gALo, nullptr, nullptr, nullptr);
        // gloss_agg = attn(q=question, kv=gloss, adjT_gq)
        run_attn(q_cur, NQ, g_cur, NG, adjTgq, (long)NQ*NG, NG,
                 g2qW + l*HFD, g2qa1 + l*HD, g2qa2 + l*HD, agg_bf);
        // question_1 (single pass)
        run_fusion(q_cur, nullptr, agg_bf, nullptr, NQ, l, 2, 1,
                   q_nxt, nullptr, nullptr, nullptr, qF);
        // question_agg = attn(q=gloss, kv=question, adj_gq)
        run_attn(g_cur, NG, q_cur, NQ, adj_gq, (long)NG*NQ, NQ,
                 q2gW + l*HFD, q2ga1 + l*HD, q2ga2 + l*HD, agg_bf);
        // gloss_2 (3-pass; emit hi/lo + transposed hi/lo for next layer's gloss_same)
        run_fusion(gA_bf, gALo, agg_bf, nullptr, NG, l, 3, 3,
                   g_nxt, gLoN, (l == 0) ? gT : nullptr, (l == 0) ? gTlo : nullptr, gF);
    }
}

// Round 4
// 793.015 us; speedup vs baseline: 1.0974x; 1.0974x over previous
//
#include <hip/hip_runtime.h>
#include <math.h>

#define NFEAT 512
#define NHEADS 8
#define HDIM 64
#define NB 4
#define NG 1024
#define NC 1024
#define NQ 256
#define NEGV -9e15f
#define CHUNKS 16
#define FF ((size_t)NFEAT*NFEAT)
#define LSTR 36   // LDS row stride (ushorts) for reg-written P tiles only

typedef _Float16 v8h __attribute__((ext_vector_type(8)));
typedef float v4f __attribute__((ext_vector_type(4)));
#define MFMA16(a,b,c) __builtin_amdgcn_mfma_f32_16x16x32_f16((a),(b),(c),0,0,0)

// async global->LDS, 16B/lane, lane-linear LDS dest (wave-uniform base + lane*16)
#define GLDS(g, l) __builtin_amdgcn_global_load_lds( \
    (__attribute__((address_space(1))) void*)(g), \
    (__attribute__((address_space(3))) void*)(l), 16, 0, 0)

// XOR swizzle for 64B-row linear LDS tiles: physical 16B slot = quad ^ ((row>>1)&3).
__device__ __forceinline__ int ldsw(int row, int quad){
    return row*32 + (((quad) ^ ((row>>1)&3)) << 3);
}

__device__ __forceinline__ float lrelu(float x){ return fmaxf(x, 0.2f*x); }
__device__ __forceinline__ unsigned short f2h(float x){ union{_Float16 h; unsigned short u;} v; v.h = (_Float16)x; return v.u; }
__device__ __forceinline__ float h2f(unsigned short u){ union{_Float16 h; unsigned short u;} v; v.u = u; return (float)v.h; }

// ============ prep: fp32 -> fp16 flat ============
__global__ __launch_bounds__(256) void cvt_h_k(const float* __restrict__ src, unsigned short* __restrict__ dst){
    int idx = blockIdx.x*256 + threadIdx.x;
    const float4* s = (const float4*)(src + (size_t)idx*8);
    float4 a = s[0], b = s[1];
    ushort4 p0{f2h(a.x),f2h(a.y),f2h(a.z),f2h(a.w)};
    ushort4 p1{f2h(b.x),f2h(b.y),f2h(b.z),f2h(b.w)};
    *(ushort4*)(dst + (size_t)idx*8) = p0;
    *(ushort4*)(dst + (size_t)idx*8 + 4) = p1;
}

// ============ prep: fp32 -> fp16 hi/lo flat ============
__global__ __launch_bounds__(256) void cvt_hl_k(const float* __restrict__ src,
    unsigned short* __restrict__ dstHi, unsigned short* __restrict__ dstLo){
    int idx = blockIdx.x*256 + threadIdx.x;
    const float4* s = (const float4*)(src + (size_t)idx*8);
    float4 a = s[0], b = s[1];
    float x[8] = {a.x,a.y,a.z,a.w,b.x,b.y,b.z,b.w};
    unsigned short hi[8], lo[8];
    #pragma unroll
    for (int j = 0; j < 8; ++j){ hi[j] = f2h(x[j]); lo[j] = f2h(x[j] - h2f(hi[j])); }
    *(ushort4*)(dstHi + (size_t)idx*8)     = ushort4{hi[0],hi[1],hi[2],hi[3]};
    *(ushort4*)(dstHi + (size_t)idx*8 + 4) = ushort4{hi[4],hi[5],hi[6],hi[7]};
    *(ushort4*)(dstLo + (size_t)idx*8)     = ushort4{lo[0],lo[1],lo[2],lo[3]};
    *(ushort4*)(dstLo + (size_t)idx*8 + 4) = ushort4{lo[4],lo[5],lo[6],lo[7]};
}

// ============ prep: fusion weights -> PACKED transposed fp16 hi/lo ============
// packed layout per group li: [c0i(8)][ktI(16)][mat(4)][row64][k32]
__global__ __launch_bounds__(256) void wtT_k(const float* __restrict__ w0, const float* __restrict__ w1,
    const float* __restrict__ w2, const float* __restrict__ w3,
    unsigned short* __restrict__ dstHi, unsigned short* __restrict__ dstLo){
    int bx = blockIdx.x;
    int mat = bx >> 6, t = bx & 63;
    int a = mat & 3, li = mat >> 2;
    const float* src = (a==0?w0:a==1?w1:a==2?w2:w3) + (size_t)li*FF;
    int fo0 = (t>>3)*64, fi0 = (t&7)*64;
    __shared__ float sT[64][65];
    int tid = threadIdx.x;
    #pragma unroll
    for (int it = 0; it < 4; ++it){
        int idx = it*256 + tid;
        int r = idx >> 4, c4 = idx & 15;
        float4 v = *(const float4*)(src + (size_t)(fi0+r)*512 + fo0 + c4*4);
        sT[r][c4*4+0]=v.x; sT[r][c4*4+1]=v.y; sT[r][c4*4+2]=v.z; sT[r][c4*4+3]=v.w;
    }
    __syncthreads();
    #pragma unroll
    for (int it = 0; it < 2; ++it){
        int idx = it*256 + tid;
        int dd = idx >> 3, c8 = idx & 7;
        unsigned short hi[8], lo[8];
        #pragma unroll
        for (int j = 0; j < 8; ++j){
            float x = sT[c8*8+j][dd];
            hi[j] = f2h(x);
            lo[j] = f2h(x - h2f(hi[j]));
        }
        int ktI = (fi0 >> 5) + (c8 >> 2);
        int k31 = (c8 & 3)*8;
        size_t oo = (size_t)li*4*FF + ((((size_t)(fo0>>6)*16 + ktI)*4 + a)*64 + dd)*32 + k31;
        *(ushort4*)(dstHi+oo)   = ushort4{hi[0],hi[1],hi[2],hi[3]};
        *(ushort4*)(dstHi+oo+4) = ushort4{hi[4],hi[5],hi[6],hi[7]};
        *(ushort4*)(dstLo+oo)   = ushort4{lo[0],lo[1],lo[2],lo[3]};
        *(ushort4*)(dstLo+oo+4) = ushort4{lo[4],lo[5],lo[6],lo[7]};
    }
}

// ============ prep: attention W repack (blocks 0..63) + wa vectors (blocks 64..79) ============
__global__ __launch_bounds__(256) void prep_attnW_k(const float* __restrict__ W,
    const float* __restrict__ a1, const float* __restrict__ a2,
    unsigned short* __restrict__ WT, float* __restrict__ wa1, float* __restrict__ wa2){
    int bx = blockIdx.x;
    int tid = threadIdx.x;
    if (bx >= 64){
        int idx = (bx - 64)*256 + tid;
        int h = idx >> 9;
        const float* Wp = W + (size_t)idx*64;
        float s1 = 0.f, s2 = 0.f;
        #pragma unroll
        for (int d = 0; d < 64; ++d){ float w = Wp[d]; s1 += w*a1[(h<<6)+d]; s2 += w*a2[(h<<6)+d]; }
        wa1[idx] = s1; wa2[idx] = s2;
        return;
    }
    int h = bx >> 3, f0 = (bx & 7)*64;
    __shared__ float sT[64][65];
    #pragma unroll
    for (int it = 0; it < 4; ++it){
        int idx = it*256 + tid;
        int r = idx >> 4, c4 = idx & 15;
        float4 v = *(const float4*)(W + ((size_t)h*512 + f0 + r)*64 + c4*4);
        sT[r][c4*4+0]=v.x; sT[r][c4*4+1]=v.y; sT[r][c4*4+2]=v.z; sT[r][c4*4+3]=v.w;
    }
    __syncthreads();
    #pragma unroll
    for (int it = 0; it < 2; ++it){
        int idx = it*256 + tid;
        int dd = idx >> 3, c8 = idx & 7;
        ushort4 p0{f2h(sT[c8*8+0][dd]),f2h(sT[c8*8+1][dd]),f2h(sT[c8*8+2][dd]),f2h(sT[c8*8+3][dd])};
        ushort4 p1{f2h(sT[c8*8+4][dd]),f2h(sT[c8*8+5][dd]),f2h(sT[c8*8+6][dd]),f2h(sT[c8*8+7][dd])};
        unsigned short* o = WT + ((size_t)h*64 + dd)*512 + f0 + c8*8;
        *(ushort4*)o = p0; *(ushort4*)(o+4) = p1;
    }
}

// ============ prep: adj_gc [b][g][c] int -> adjT fp16 [b][c][g] ============
__global__ __launch_bounds__(256) void adjT_h_k(const int* __restrict__ adj, unsigned short* __restrict__ dst){
    int b = blockIdx.z;
    int c0 = blockIdx.x*64, g0 = blockIdx.y*64;
    __shared__ int sI[64][65];
    int tid = threadIdx.x;
    #pragma unroll
    for (int it = 0; it < 4; ++it){
        int idx = it*256 + tid;
        int r = idx >> 4, c4 = idx & 15;
        int4 v = *(const int4*)(adj + ((size_t)b*NG + g0 + r)*NC + c0 + c4*4);
        sI[r][c4*4+0]=v.x; sI[r][c4*4+1]=v.y; sI[r][c4*4+2]=v.z; sI[r][c4*4+3]=v.w;
    }
    __syncthreads();
    #pragma unroll
    for (int it = 0; it < 2; ++it){
        int idx = it*256 + tid;
        int dd = idx >> 3, c8 = idx & 7;
        ushort4 p0, p1;
        #pragma unroll
        for (int j = 0; j < 4; ++j) (&p0.x)[j] = sI[c8*8+j][dd] > 0 ? (unsigned short)0x3C00 : (unsigned short)0;
        #pragma unroll
        for (int j = 0; j < 4; ++j) (&p1.x)[j] = sI[c8*8+4+j][dd] > 0 ? (unsigned short)0x3C00 : (unsigned short)0;
        unsigned short* o = dst + ((size_t)b*NC + c0 + dd)*NG + g0 + c8*8;
        *(ushort4*)o = p0; *(ushort4*)(o+4) = p1;
    }
}

// ============ prep: adj_gq [b][g][q] int -> adjT int [b][q][g] ============
__global__ __launch_bounds__(256) void adjT_int_k(const int* __restrict__ adj, int* __restrict__ dst){
    int b = blockIdx.z;
    int q0 = blockIdx.x*64, g0 = blockIdx.y*64;
    __shared__ int sI[64][65];
    int tid = threadIdx.x;
    #pragma unroll
    for (int it = 0; it < 4; ++it){
        int idx = it*256 + tid;
        int r = idx >> 4, c4 = idx & 15;
        int4 v = *(const int4*)(adj + ((size_t)b*NG + g0 + r)*NQ + q0 + c4*4);
        sI[r][c4*4+0]=v.x; sI[r][c4*4+1]=v.y; sI[r][c4*4+2]=v.z; sI[r][c4*4+3]=v.w;
    }
    __syncthreads();
    #pragma unroll
    for (int it = 0; it < 4; ++it){
        int idx = it*256 + tid;
        int dd = idx >> 4, c4 = idx & 15;
        int4 v{sI[c4*4+0][dd], sI[c4*4+1][dd], sI[c4*4+2][dd], sI[c4*4+3][dd]};
        *(int4*)(dst + ((size_t)b*NQ + q0 + dd)*NG + g0 + c4*4) = v;
    }
}

// ============ prep: row-ballot bitmask from int array (cols % 64 == 0) ============
// each block covers 16 segments of 64 ints
__global__ __launch_bounds__(256) void bm_int_k(const int* __restrict__ adj, unsigned long long* __restrict__ out){
    int w = threadIdx.x >> 6, lane = threadIdx.x & 63;
    #pragma unroll
    for (int i = 0; i < 4; ++i){
        size_t seg = (size_t)blockIdx.x*16 + i*4 + w;
        int v = adj[seg*64 + lane];
        unsigned long long m = __ballot(v > 0);
        if (lane == 0) out[seg] = m;
    }
}

// ============ prep: row-ballot bitmask from fp16 0/1 array ============
__global__ __launch_bounds__(256) void bm_h_k(const unsigned short* __restrict__ adj, unsigned long long* __restrict__ out){
    int w = threadIdx.x >> 6, lane = threadIdx.x & 63;
    #pragma unroll
    for (int i = 0; i < 4; ++i){
        size_t seg = (size_t)blockIdx.x*16 + i*4 + w;
        unsigned short v = adj[seg*64 + lane];
        unsigned long long m = __ballot(v != 0);
        if (lane == 0) out[seg] = m;
    }
}

// ============ prep: fp32 act [b][rows][512] -> transposed hi/lo fp16 [b][512][rows] ============
__global__ __launch_bounds__(256) void actT_hl_k(const float* __restrict__ src,
    unsigned short* __restrict__ dstHi, unsigned short* __restrict__ dstLo, int Nrows){
    int b = blockIdx.z;
    int f0 = blockIdx.x*64, g0 = blockIdx.y*64;
    __shared__ float sF[64][65];
    int tid = threadIdx.x;
    #pragma unroll
    for (int it = 0; it < 4; ++it){
        int idx = it*256 + tid;
        int r = idx >> 4, c4 = idx & 15;
        float4 v = *(const float4*)(src + ((size_t)b*Nrows + g0 + r)*512 + f0 + c4*4);
        sF[r][c4*4+0]=v.x; sF[r][c4*4+1]=v.y; sF[r][c4*4+2]=v.z; sF[r][c4*4+3]=v.w;
    }
    __syncthreads();
    #pragma unroll
    for (int it = 0; it < 2; ++it){
        int idx = it*256 + tid;
        int dd = idx >> 3, c8 = idx & 7;
        unsigned short hi[8], lo[8];
        #pragma unroll
        for (int j = 0; j < 8; ++j){
            float x = sF[c8*8+j][dd];
            hi[j] = f2h(x);
            lo[j] = f2h(x - h2f(hi[j]));
        }
        size_t oo = ((size_t)b*512 + f0 + dd)*Nrows + g0 + c8*8;
        *(ushort4*)(dstHi+oo)   = ushort4{hi[0],hi[1],hi[2],hi[3]};
        *(ushort4*)(dstHi+oo+4) = ushort4{hi[4],hi[5],hi[6],hi[7]};
        *(ushort4*)(dstLo+oo)   = ushort4{lo[0],lo[1],lo[2],lo[3]};
        *(ushort4*)(dstLo+oo+4) = ushort4{lo[4],lo[5],lo[6],lo[7]};
    }
}

// ============ scores for q and kv in one launch ============
__global__ __launch_bounds__(256) void scores2_k(
    const unsigned short* __restrict__ qX, const float* __restrict__ wa1, float* __restrict__ qs, int nQblocks,
    const unsigned short* __restrict__ kX, const float* __restrict__ wa2, float* __restrict__ ks){
    int lane = threadIdx.x & 63;
    const unsigned short* X; const float* wa; float* sc; int row;
    if ((int)blockIdx.x < nQblocks){ X = qX; wa = wa1; sc = qs; row = blockIdx.x*4 + (threadIdx.x >> 6); }
    else { X = kX; wa = wa2; sc = ks; row = (blockIdx.x - nQblocks)*4 + (threadIdx.x >> 6); }
    const unsigned short* Xr = X + (size_t)row*NFEAT;
    float p[NHEADS];
    #pragma unroll
    for (int h = 0; h < NHEADS; ++h) p[h] = 0.f;
    #pragma unroll
    for (int c = 0; c < 8; ++c){
        float x = h2f(Xr[(c<<6) + lane]);
        #pragma unroll
        for (int h = 0; h < NHEADS; ++h) p[h] += x * wa[(h<<9) + (c<<6) + lane];
    }
    #pragma unroll
    for (int h = 0; h < NHEADS; ++h){
        float v = p[h];
        #pragma unroll
        for (int off = 32; off > 0; off >>= 1) v += __shfl_xor(v, off);
        if (lane == 0) sc[(size_t)row*NHEADS + h] = v;
    }
}

// ============ merged online colmax+colsum via bitmask: per-chunk (cm, sum) ============
__global__ __launch_bounds__(256) void colstat_part_k(const unsigned* __restrict__ bmM, int N32,
    const float* __restrict__ qs, const float* __restrict__ ks,
    float* __restrict__ pcm, float* __restrict__ psum, int N, int M){
    int b = blockIdx.z, ch = blockIdx.y;
    int ml = threadIdx.x & 63; int m = blockIdx.x*64 + ml;
    int g = threadIdx.x >> 6;
    int chunk = N / CHUNKS, subl = chunk >> 2;
    int n0 = ch*chunk + g*subl;
    __shared__ float sQ[64][8];
    for (int t2 = threadIdx.x; t2 < chunk*8; t2 += 256)
        sQ[t2>>3][t2&7] = qs[((size_t)b*N + ch*chunk)*8 + t2];
    float ksv[8];
    size_t mo = ((size_t)b*M + m)*8;
    #pragma unroll
    for (int h = 0; h < 8; ++h) ksv[h] = ks[mo+h];
    unsigned word = bmM[((size_t)b*M + m)*N32 + (n0>>5)];
    unsigned bits = (word >> (n0 & 31)) & ((1u << subl) - 1u);
    __syncthreads();
    int nb = g*subl;
    float mx[8];
    #pragma unroll
    for (int h = 0; h < 8; ++h) mx[h] = -INFINITY;
    for (int i = 0; i < subl; ++i){
        if ((bits >> i) & 1){
            #pragma unroll
            for (int h = 0; h < 8; ++h) mx[h] = fmaxf(mx[h], sQ[nb+i][h]);
        }
    }
    float cm[8], s[8];
    #pragma unroll
    for (int h = 0; h < 8; ++h){
        cm[h] = bits ? lrelu(mx[h] + ksv[h]) : NEGV;
        s[h] = 0.f;
    }
    for (int i = 0; i < subl; ++i){
        bool on = (bits >> i) & 1;
        #pragma unroll
        for (int h = 0; h < 8; ++h){
            float e = on ? lrelu(sQ[nb+i][h] + ksv[h]) : NEGV;
            s[h] += __expf(e - cm[h]);
        }
    }
    __shared__ float scm[4][64][8], ssm[4][64][8];
    #pragma unroll
    for (int h = 0; h < 8; ++h){ scm[g][ml][h] = cm[h]; ssm[g][ml][h] = s[h]; }
    __syncthreads();
    if (g == 0){
        #pragma unroll
        for (int h = 0; h < 8; ++h){
            float c0 = scm[0][ml][h], c1 = scm[1][ml][h], c2 = scm[2][ml][h], c3 = scm[3][ml][h];
            float CM = fmaxf(fmaxf(c0, c1), fmaxf(c2, c3));
            float S = ssm[0][ml][h]*__expf(c0-CM) + ssm[1][ml][h]*__expf(c1-CM)
                    + ssm[2][ml][h]*__expf(c2-CM) + ssm[3][ml][h]*__expf(c3-CM);
            size_t o = (((size_t)b*CHUNKS + ch)*M + m)*8 + h;
            pcm[o] = CM; psum[o] = S;
        }
    }
}

// ============ merged finalize: chunk-combine + stat repack -> ksh/cmh/ish [b][8][M] ============
__global__ __launch_bounds__(256) void colfin_k(const float* __restrict__ pcm, const float* __restrict__ psum,
    const float* __restrict__ ks, float* __restrict__ ksh, float* __restrict__ cmh,
    float* __restrict__ ish, int M){
    int idx = blockIdx.x*256 + threadIdx.x;
    int m8 = M*8;
    int b = idx / m8, rem = idx - b*m8;
    int m = rem >> 3, h = rem & 7;
    size_t base = (size_t)b*CHUNKS*m8 + rem;
    float c[CHUNKS], s[CHUNKS];
    #pragma unroll
    for (int ch = 0; ch < CHUNKS; ++ch){
        c[ch] = pcm[base + (size_t)ch*m8];
        s[ch] = psum[base + (size_t)ch*m8];
    }
    float CM = c[0];
    #pragma unroll
    for (int ch = 1; ch < CHUNKS; ++ch) CM = fmaxf(CM, c[ch]);
    float S = 0.f;
    #pragma unroll
    for (int ch = 0; ch < CHUNKS; ++ch) S += s[ch]*__expf(c[ch] - CM);
    size_t o = ((size_t)b*8 + h)*M + m;
    ksh[o] = ks[idx]; cmh[o] = CM; ish[o] = 1.f/S;
}

// ============ fused fusion MFMA: 64x64 tile, packed weights, GLDS staging ============
template<int MULTI>
__global__ __launch_bounds__(256) void fusion_all_k(
    const unsigned short* __restrict__ aHi, const unsigned short* __restrict__ aLo,
    const unsigned short* __restrict__ bHi, const unsigned short* __restrict__ bLo,
    const unsigned short* __restrict__ Whi, const unsigned short* __restrict__ Wlo,
    unsigned short* __restrict__ dst, unsigned short* __restrict__ dstLo,
    unsigned short* __restrict__ dstT, unsigned short* __restrict__ dstTLo,
    float* __restrict__ dstF, int rows){
    // T1: group the 8 c0-blocks of each (r0,b) panel onto one XCD.
    int nY = rows >> 6;
    int ppg = (nY * NB) >> 3;
    int F = blockIdx.x;
    int xcd = F & 7, t = F >> 3;
    int c0i = t / ppg;
    int p = xcd + ((t - c0i*ppg) << 3);
    int r0 = (p % nY) << 6, c0 = c0i << 6;
    int b = p / nY;
    int tid = threadIdx.x;
    __shared__ alignas(16) unsigned short aHs[2048], bHs[2048];
    __shared__ alignas(16) unsigned short aLs[MULTI ? 2048 : 16], bLs[MULTI ? 2048 : 16];
    __shared__ alignas(16) unsigned short wHs[8192];
    __shared__ alignas(16) unsigned short wLs[MULTI ? 8192 : 16];
    size_t actOff = (size_t)b*rows*512;
    const unsigned short* aHG = aHi + actOff;
    const unsigned short* bHG = bHi + actOff;
    const unsigned short* aLG = aLo ? aLo + actOff : nullptr;
    const unsigned short* bLG = bLo ? bLo + actOff : nullptr;
    bool hasALo = MULTI && (aLG != nullptr);
    bool hasBLo = MULTI && (bLG != nullptr);
    int w = tid >> 6, lane = tid & 63;
    int wr = w >> 1, wc = w & 1;
    int lrow = lane & 15, quad = lane >> 4;
    int sr = tid >> 2;
    int sq = (tid & 3) ^ ((sr >> 1) & 3);
    size_t aRow = (size_t)(r0 + sr)*512 + sq*8;
    // packed weight base: [c0i][ktI][mat][row64][k32]
    size_t wPk = (size_t)c0i*16*8192 + (size_t)sr*32 + sq*8;
    unsigned short* ldsA  = &aHs[w << 9];
    unsigned short* ldsB  = &bHs[w << 9];
    unsigned short* ldsAL = &aLs[MULTI ? (w << 9) : 0];
    unsigned short* ldsBL = &bLs[MULTI ? (w << 9) : 0];
    v4f accN[2][2], accF[2][2];
    #pragma unroll
    for (int r = 0; r < 2; ++r)
        #pragma unroll
        for (int cf = 0; cf < 2; ++cf){ accN[r][cf] = (v4f)0.f; accF[r][cf] = (v4f)0.f; }
    for (int kt = 0; kt < 512; kt += 32){
        __syncthreads();
        GLDS(aHG + aRow + kt, ldsA);
        GLDS(bHG + aRow + kt, ldsB);
        if (hasALo) GLDS(aLG + aRow + kt, ldsAL);
        if (hasBLo) GLDS(bLG + aRow + kt, ldsBL);
        size_t wk = wPk + (size_t)(kt >> 5)*8192;
        #pragma unroll
        for (int m = 0; m < 4; ++m){
            GLDS(Whi + wk + (m<<11), &wHs[(m<<11) + (w<<9)]);
            if (MULTI) GLDS(Wlo + wk + (m<<11), &wLs[MULTI ? ((m<<11) + (w<<9)) : 0]);
        }
        __syncthreads();
        v8h ah[2], bh[2], al[2], bl[2];
        #pragma unroll
        for (int r = 0; r < 2; ++r){
            int ao = ldsw(wr*32 + r*16 + lrow, quad);
            ah[r] = *(const v8h*)&aHs[ao];
            bh[r] = *(const v8h*)&bHs[ao];
            if (hasALo) al[r] = *(const v8h*)&aLs[ao];
            if (hasBLo) bl[r] = *(const v8h*)&bLs[ao];
        }
        #pragma unroll
        for (int cf = 0; cf < 2; ++cf){
            int wo = ldsw(wc*32 + cf*16 + lrow, quad);
            v8h w0 = *(const v8h*)&wHs[wo];
            v8h w1 = *(const v8h*)&wHs[2048 + wo];
            v8h w2 = *(const v8h*)&wHs[4096 + wo];
            v8h w3 = *(const v8h*)&wHs[6144 + wo];
            v8h l0, l1, l2, l3;
            if (MULTI){
                l0 = *(const v8h*)&wLs[wo];
                l1 = *(const v8h*)&wLs[2048 + wo];
                l2 = *(const v8h*)&wLs[4096 + wo];
                l3 = *(const v8h*)&wLs[6144 + wo];
            }
            #pragma unroll
            for (int r = 0; r < 2; ++r){
                accN[r][cf] = MFMA16(ah[r], w0, accN[r][cf]);
                accN[r][cf] = MFMA16(bh[r], w1, accN[r][cf]);
                accF[r][cf] = MFMA16(ah[r], w2, accF[r][cf]);
                accF[r][cf] = MFMA16(bh[r], w3, accF[r][cf]);
                if (MULTI){
                    if (hasALo){ accN[r][cf] = MFMA16(al[r], w0, accN[r][cf]); accF[r][cf] = MFMA16(al[r], w2, accF[r][cf]); }
                    if (hasBLo){ accN[r][cf] = MFMA16(bl[r], w1, accN[r][cf]); accF[r][cf] = MFMA16(bl[r], w3, accF[r][cf]); }
                    accN[r][cf] = MFMA16(ah[r], l0, accN[r][cf]);
                    accN[r][cf] = MFMA16(bh[r], l1, accN[r][cf]);
                    accF[r][cf] = MFMA16(ah[r], l2, accF[r][cf]);
                    accF[r][cf] = MFMA16(bh[r], l3, accF[r][cf]);
                }
            }
        }
    }
    #pragma unroll
    for (int r = 0; r < 2; ++r)
        #pragma unroll
        for (int cf = 0; cf < 2; ++cf){
            int colg = c0 + wc*32 + cf*16 + lrow;
            int rbase = r0 + wr*32 + r*16 + quad*4;
            float o4[4];
            #pragma unroll
            for (int reg = 0; reg < 4; ++reg){
                float f = 1.f/(1.f + __expf(-accF[r][cf][reg]));
                size_t ai = (size_t)(rbase+reg)*512 + colg;
                float ao = h2f(aHG[ai]);
                if (aLG) ao += h2f(aLG[ai]);
                o4[reg] = f*accN[r][cf][reg] + (1.f - f)*ao;
                size_t oo = ((size_t)b*rows + rbase + reg)*512 + colg;
                unsigned short hv = f2h(o4[reg]);
                dst[oo] = hv;
                if (dstLo) dstLo[oo] = f2h(o4[reg] - h2f(hv));
                if (dstF) dstF[oo] = o4[reg];
            }
            if (dstT){
                unsigned short h0 = f2h(o4[0]), h1 = f2h(o4[1]), h2 = f2h(o4[2]), h3 = f2h(o4[3]);
                size_t to = ((size_t)b*512 + colg)*rows + rbase;
                *(ushort4*)&dstT[to] = ushort4{h0,h1,h2,h3};
                if (dstTLo)
                    *(ushort4*)&dstTLo[to] = ushort4{f2h(o4[0]-h2f(h0)), f2h(o4[1]-h2f(h1)),
                                                     f2h(o4[2]-h2f(h2)), f2h(o4[3]-h2f(h3))};
            }
        }
}

// ============ generic MFMA GEMM (64-row tiles, double-buffered) ============
__global__ __launch_bounds__(256) void gemmT_mfma_k(
    const unsigned short* __restrict__ A, size_t aStride,
    const unsigned short* __restrict__ BT, const unsigned short* __restrict__ BT2, size_t bStride,
    int K, int rowsPB,
    unsigned short* __restrict__ outRM, unsigned short* __restrict__ outLo,
    unsigned short* __restrict__ outT){
    int b = blockIdx.z;
    int r0 = blockIdx.y*64, c0 = blockIdx.x*64;
    int tid = threadIdx.x;
    __shared__ alignas(16) unsigned short aS[2][2048], bS[2][2048];
    const unsigned short* aG = A + (size_t)b*aStride;
    const unsigned short* bG0 = BT + (size_t)b*bStride;
    const unsigned short* bG1 = BT2 ? BT2 + (size_t)b*bStride : nullptr;
    int w = tid >> 6, lane = tid & 63;
    int lrow = lane & 15, quad = lane >> 4;
    int sr = tid >> 2;
    int sq = (tid & 3) ^ ((sr >> 1) & 3);
    size_t aRow = (size_t)(r0 + sr)*K + sq*8;
    size_t bRow = (size_t)(c0 + sr)*K + sq*8;
    int spp = K >> 5;
    int nsteps = (BT2 ? 2 : 1)*spp;
    v4f acc[4];
    #pragma unroll
    for (int cf = 0; cf < 4; ++cf) acc[cf] = (v4f)0.f;
    GLDS(aG + aRow, &aS[0][w << 9]);
    GLDS(bG0 + bRow, &bS[0][w << 9]);
    __syncthreads();
    int buf = 0;
    for (int s = 0; s < nsteps; ++s){
        int sn = s + 1;
        if (sn < nsteps){
            int ktn = ((sn >= spp) ? (sn - spp) : sn) << 5;
            const unsigned short* bgn = (sn >= spp) ? bG1 : bG0;
            GLDS(aG + aRow + ktn, &aS[buf^1][w << 9]);
            GLDS(bgn + bRow + ktn, &bS[buf^1][w << 9]);
        }
        v8h af = *(const v8h*)&aS[buf][ldsw(w*16 + lrow, quad)];
        #pragma unroll
        for (int cf = 0; cf < 4; ++cf){
            v8h bf = *(const v8h*)&bS[buf][ldsw(cf*16 + lrow, quad)];
            acc[cf] = MFMA16(af, bf, acc[cf]);
        }
        __syncthreads();
        buf ^= 1;
    }
    #pragma unroll
    for (int cf = 0; cf < 4; ++cf){
        int colg = c0 + cf*16 + lrow;
        int rbase = r0 + w*16 + quad*4;
        if (outRM){
            #pragma unroll
            for (int reg = 0; reg < 4; ++reg){
                float v = acc[cf][reg];
                unsigned short hv = f2h(v);
                size_t oo = ((size_t)b*rowsPB + rbase + reg)*512 + colg;
                outRM[oo] = hv;
                if (outLo) outLo[oo] = f2h(v - h2f(hv));
            }
        }
        if (outT){
            ushort4 pk{f2h(acc[cf][0]), f2h(acc[cf][1]), f2h(acc[cf][2]), f2h(acc[cf][3])};
            *(ushort4*)&outT[((size_t)b*512 + colg)*rowsPB + rbase] = pk;
        }
    }
}

// ============ attention output MFMA: bitmask adj, double-buffered, reg prefetch ============
__global__ __launch_bounds__(256) void attn_mfma_k(const unsigned* __restrict__ bmN, int M32,
    const float* __restrict__ qs, const float* __restrict__ ksh, const float* __restrict__ cmh,
    const float* __restrict__ ish, const unsigned short* __restrict__ WkT,
    unsigned short* __restrict__ outp, int N, int M){
    int bh = blockIdx.y; int b = bh >> 3, h = bh & 7;
    int n0 = blockIdx.x*64;
    int tid = threadIdx.x;
    __shared__ unsigned short pS[2*64*LSTR];
    __shared__ alignas(16) unsigned short wS[2*2048];
    __shared__ float qsS[64];
    if (tid < 64) qsS[tid] = qs[((size_t)b*N + n0 + tid)*8 + h];
    const float* ksb = ksh + ((size_t)b*8 + h)*M;
    const float* cmb = cmh + ((size_t)b*8 + h)*M;
    const float* isb = ish + ((size_t)b*8 + h)*M;
    const unsigned short* wkb = WkT + ((size_t)b*512 + h*64)*M;
    int w = tid >> 6, lane = tid & 63;
    int lrow = lane & 15, quad = lane >> 4;
    int pn = tid >> 2, pm = (tid & 3)*8;
    int sr = tid >> 2;
    int sq = (tid & 3) ^ ((sr >> 1) & 3);
    const unsigned* bmrow = bmN + ((size_t)b*N + n0 + pn)*M32;
    v4f acc[4];
    #pragma unroll
    for (int cf = 0; cf < 4; ++cf) acc[cf] = (v4f)0.f;
    uint2 CW = *(const uint2*)(bmrow);
    float4 K0 = *(const float4*)(ksb + pm), K1 = *(const float4*)(ksb + pm + 4);
    float4 C0 = *(const float4*)(cmb + pm), C1 = *(const float4*)(cmb + pm + 4);
    float4 I0 = *(const float4*)(isb + pm), I1 = *(const float4*)(isb + pm + 4);
    uint2 NW; float4 LK0, LK1, LC0, LC1, LI0, LI1;
    __syncthreads();          // qsS visible
    float qv = qsS[pn];
    for (int mt = 0; mt < M; mt += 64){
        int mtB = mt + 32;
        int mtN = (mt + 64 < M) ? (mt + 64) : 0;
        // ---- sub-step 0: buf0, compute from CW.x, prefetch stats(mtB) ----
        GLDS(wkb + (size_t)sr*M + mt + sq*8, &wS[w << 9]);
        LK0 = *(const float4*)(ksb + mtB + pm); LK1 = *(const float4*)(ksb + mtB + pm + 4);
        LC0 = *(const float4*)(cmb + mtB + pm); LC1 = *(const float4*)(cmb + mtB + pm + 4);
        LI0 = *(const float4*)(isb + mtB + pm); LI1 = *(const float4*)(isb + mtB + pm + 4);
        {
            unsigned bb = (CW.x >> pm) & 0xffu;
            float p[8];
            const float* kk0 = &K0.x; const float* kk1 = &K1.x;
            const float* cc0 = &C0.x; const float* cc1 = &C1.x;
            const float* ii0 = &I0.x; const float* ii1 = &I1.x;
            #pragma unroll
            for (int j = 0; j < 4; ++j){
                float e = ((bb >> j) & 1) ? lrelu(qv + kk0[j]) : NEGV;
                p[j] = __expf(e - cc0[j]) * ii0[j];
            }
            #pragma unroll
            for (int j = 0; j < 4; ++j){
                float e = ((bb >> (4+j)) & 1) ? lrelu(qv + kk1[j]) : NEGV;
                p[4+j] = __expf(e - cc1[j]) * ii1[j];
            }
            *(ushort4*)&pS[pn*LSTR + pm]     = ushort4{f2h(p[0]), f2h(p[1]), f2h(p[2]), f2h(p[3])};
            *(ushort4*)&pS[pn*LSTR + pm + 4] = ushort4{f2h(p[4]), f2h(p[5]), f2h(p[6]), f2h(p[7])};
        }
        __syncthreads();
        {
            v8h af = *(const v8h*)&pS[(w*16 + lrow)*LSTR + quad*8];
            #pragma unroll
            for (int cf = 0; cf < 4; ++cf){
                v8h bf = *(const v8h*)&wS[ldsw(cf*16 + lrow, quad)];
                acc[cf] = MFMA16(af, bf, acc[cf]);
            }
        }
        // ---- sub-step 1: buf1, compute from CW.y, prefetch stats+mask(mtN) ----
        GLDS(wkb + (size_t)sr*M + mtB + sq*8, &wS[2048 + (w << 9)]);
        NW = *(const uint2*)(bmrow + (mtN >> 5));
        K0 = *(const float4*)(ksb + mtN + pm); K1 = *(const float4*)(ksb + mtN + pm + 4);
        C0 = *(const float4*)(cmb + mtN + pm); C1 = *(const float4*)(cmb + mtN + pm + 4);
        I0 = *(const float4*)(isb + mtN + pm); I1 = *(const float4*)(isb + mtN + pm + 4);
        {
            unsigned bb = (CW.y >> pm) & 0xffu;
            float p[8];
            const float* kk0 = &LK0.x; const float* kk1 = &LK1.x;
            const float* cc0 = &LC0.x; const float* cc1 = &LC1.x;
            const float* ii0 = &LI0.x; const float* ii1 = &LI1.x;
            #pragma unroll
            for (int j = 0; j < 4; ++j){
                float e = ((bb >> j) & 1) ? lrelu(qv + kk0[j]) : NEGV;
                p[j] = __expf(e - cc0[j]) * ii0[j];
            }
            #pragma unroll
            for (int j = 0; j < 4; ++j){
                float e = ((bb >> (4+j)) & 1) ? lrelu(qv + kk1[j]) : NEGV;
                p[4+j] = __expf(e - cc1[j]) * ii1[j];
            }
            *(ushort4*)&pS[2304 + pn*LSTR + pm]     = ushort4{f2h(p[0]), f2h(p[1]), f2h(p[2]), f2h(p[3])};
            *(ushort4*)&pS[2304 + pn*LSTR + pm + 4] = ushort4{f2h(p[4]), f2h(p[5]), f2h(p[6]), f2h(p[7])};
        }
        __syncthreads();
        {
            v8h af = *(const v8h*)&pS[2304 + (w*16 + lrow)*LSTR + quad*8];
            #pragma unroll
            for (int cf = 0; cf < 4; ++cf){
                v8h bf = *(const v8h*)&wS[2048 + ldsw(cf*16 + lrow, quad)];
                acc[cf] = MFMA16(af, bf, acc[cf]);
            }
        }
        CW = NW;
    }
    #pragma unroll
    for (int cf = 0; cf < 4; ++cf){
        int colg = h*64 + cf*16 + lrow;
        int rbase = n0 + w*16 + quad*4;
        #pragma unroll
        for (int reg = 0; reg < 4; ++reg){
            float v = acc[cf][reg];
            v = (v > 0.f) ? v : (__expf(v) - 1.f);
            outp[((size_t)b*N + rbase + reg)*512 + colg] = f2h(v);
        }
    }
}

extern "C" void kernel_launch(void* const* d_in, const int* in_sizes, int n_in,
                              void* d_out, int out_size, void* d_ws, size_t ws_size,
                              hipStream_t stream){
    const float* in_gloss = (const float*)d_in[0];
    const float* in_clip  = (const float*)d_in[1];
    const float* in_q     = (const float*)d_in[2];
    const int*   adj_gc   = (const int*)d_in[3];
    const int*   adj_gq   = (const int*)d_in[4];
    const float* c2gW  = (const float*)d_in[5];
    const float* c2ga1 = (const float*)d_in[6];
    const float* c2ga2 = (const float*)d_in[7];
    const float* g2qW  = (const float*)d_in[8];
    const float* g2qa1 = (const float*)d_in[9];
    const float* g2qa2 = (const float*)d_in[10];
    const float* q2gW  = (const float*)d_in[11];
    const float* q2ga1 = (const float*)d_in[12];
    const float* q2ga2 = (const float*)d_in[13];
    const float* fusW  = (const float*)d_in[14];
    const float* fusU  = (const float*)d_in[15];
    const float* fusWf = (const float*)d_in[16];
    const float* fusUf = (const float*)d_in[17];
    float* out = (float*)d_out;
    float* out_gloss = out;
    float* out_clip  = out + (size_t)NB*NG*NFEAT;
    float* out_q     = out + (size_t)NB*NG*NFEAT*2;

    char* wsB = (char*)d_ws;
    size_t off = 0;
    auto alloc = [&](size_t bytes){ void* p = wsB + off; off += (bytes + 255) & ~(size_t)255; return p; };
    float* wa1   = (float*)alloc(4096*4);
    float* wa2   = (float*)alloc(4096*4);
    float* qsb   = (float*)alloc((size_t)NB*NG*8*4);
    float* ksb   = (float*)alloc((size_t)NB*NG*8*4);
    float* ksh   = (float*)alloc((size_t)NB*NG*8*4);
    float* cmh   = (float*)alloc((size_t)NB*NG*8*4);
    float* ish   = (float*)alloc((size_t)NB*NG*8*4);
    float* pmaxb = (float*)alloc((size_t)NB*CHUNKS*NG*8*4);
    float* psumb = (float*)alloc((size_t)NB*CHUNKS*NG*8*4);
    unsigned short* WflatT  = (unsigned short*)alloc((size_t)NFEAT*NFEAT*2);
    unsigned short* wtAll   = (unsigned short*)alloc((size_t)32*FF*2);
    unsigned short* wtAllLo = (unsigned short*)alloc((size_t)32*FF*2);
    unsigned short* adjTgc  = (unsigned short*)alloc((size_t)NB*NC*NG*2);
    unsigned short* g_bf0   = (unsigned short*)alloc((size_t)NB*NG*NFEAT*2);
    unsigned short* gLo0    = (unsigned short*)alloc((size_t)NB*NG*NFEAT*2);
    unsigned short* g_bf1   = (unsigned short*)alloc((size_t)NB*NG*NFEAT*2);
    unsigned short* gLo1    = (unsigned short*)alloc((size_t)NB*NG*NFEAT*2);
    unsigned short* gT      = (unsigned short*)alloc((size_t)NB*NFEAT*NG*2);
    unsigned short* gTlo    = (unsigned short*)alloc((size_t)NB*NFEAT*NG*2);
    unsigned short* gA_bf   = (unsigned short*)alloc((size_t)NB*NG*NFEAT*2);
    unsigned short* gALo    = (unsigned short*)alloc((size_t)NB*NG*NFEAT*2);
    unsigned short* c_bf0   = (unsigned short*)alloc((size_t)NB*NC*NFEAT*2);
    unsigned short* cLo0    = (unsigned short*)alloc((size_t)NB*NC*NFEAT*2);
    unsigned short* c_bf1   = (unsigned short*)alloc((size_t)NB*NC*NFEAT*2);
    unsigned short* cLo1    = (unsigned short*)alloc((size_t)NB*NC*NFEAT*2);
    unsigned short* q_bf0   = (unsigned short*)alloc((size_t)NB*NQ*NFEAT*2);
    unsigned short* q_bf1   = (unsigned short*)alloc((size_t)NB*NQ*NFEAT*2);
    unsigned short* agg_bf  = (unsigned short*)alloc((size_t)NB*NG*NFEAT*2);
    unsigned short* aggLo   = (unsigned short*)alloc((size_t)NB*NG*NFEAT*2);
    unsigned short* WkT     = (unsigned short*)alloc((size_t)NB*NFEAT*NG*2);
    int* adjTgq = (int*)alloc((size_t)NB*NQ*NG*4);
    unsigned* bm_gc = (unsigned*)alloc((size_t)NB*NG*(NC/32)*4);
    unsigned* bm_cg = (unsigned*)alloc((size_t)NB*NC*(NG/32)*4);
    unsigned* bm_gq = (unsigned*)alloc((size_t)NB*NG*(NQ/32)*4);
    unsigned* bm_qg = (unsigned*)alloc((size_t)NB*NQ*(NG/32)*4);
    (void)ws_size; (void)in_sizes; (void)n_in; (void)out_size;

    const size_t HFD = (size_t)NHEADS*NFEAT*HDIM;
    const size_t HD  = (size_t)NHEADS*HDIM;

    // ---- prep ----
    wtT_k<<<2048, 256, 0, stream>>>(fusW, fusU, fusWf, fusUf, wtAll, wtAllLo);
    adjT_h_k<<<dim3(NC/64, NG/64, NB), 256, 0, stream>>>(adj_gc, adjTgc);
    adjT_int_k<<<dim3(NQ/64, NG/64, NB), 256, 0, stream>>>(adj_gq, adjTgq);
    bm_int_k<<<(NB*NG*NC/64)/16, 256, 0, stream>>>(adj_gc, (unsigned long long*)bm_gc);
    bm_int_k<<<(NB*NG*NQ/64)/16, 256, 0, stream>>>(adj_gq, (unsigned long long*)bm_gq);
    bm_int_k<<<(NB*NQ*NG/64)/16, 256, 0, stream>>>(adjTgq, (unsigned long long*)bm_qg);
    bm_h_k<<<(NB*NC*NG/64)/16, 256, 0, stream>>>(adjTgc, (unsigned long long*)bm_cg);
    cvt_hl_k<<<(NB*NG*NFEAT)/2048, 256, 0, stream>>>(in_gloss, g_bf0, gLo0);
    cvt_hl_k<<<(NB*NC*NFEAT)/2048, 256, 0, stream>>>(in_clip,  c_bf0, cLo0);
    cvt_h_k<<<(NB*NQ*NFEAT)/2048, 256, 0, stream>>>(in_q,     q_bf0);
    actT_hl_k<<<dim3(8, NG/64, NB), 256, 0, stream>>>(in_gloss, gT, gTlo, NG);

    auto run_attn = [&](const unsigned short* qX, int N, const unsigned short* kvX, int M,
                        const unsigned* bmNM, const unsigned* bmMN,
                        const float* W, const float* a1, const float* a2, unsigned short* dst){
        prep_attnW_k<<<80, 256, 0, stream>>>(W, a1, a2, WflatT, wa1, wa2);
        scores2_k<<<(NB*(N+M))/4, 256, 0, stream>>>(qX, wa1, qsb, (NB*N)/4, kvX, wa2, ksb);
        gemmT_mfma_k<<<dim3(8, M/64, NB), 256, 0, stream>>>(kvX, (size_t)M*512, WflatT, nullptr, 0,
                                                            512, M, nullptr, nullptr, WkT);
        colstat_part_k<<<dim3(M/64, CHUNKS, NB), 256, 0, stream>>>(bmMN, N/32, qsb, ksb,
                                                                   pmaxb, psumb, N, M);
        colfin_k<<<(NB*M*8)/256, 256, 0, stream>>>(pmaxb, psumb, ksb, ksh, cmh, ish, M);
        attn_mfma_k<<<dim3(N/64, NB*8), 256, 0, stream>>>(bmNM, M/32, qsb, ksh, cmh, ish,
                                                          WkT, dst, N, M);
    };
    auto run_fusion = [&](const unsigned short* a, const unsigned short* aLo,
                          const unsigned short* bb, const unsigned short* bLo, int rows,
                          int l, int i, int npass,
                          unsigned short* dst, unsigned short* dstLo,
                          unsigned short* dstT, unsigned short* dstTLo, float* dstF){
        const unsigned short* Whi = wtAll   + (size_t)((l*4 + i)*4)*FF;
        const unsigned short* Wlo = wtAllLo + (size_t)((l*4 + i)*4)*FF;
        if (npass == 3)
            fusion_all_k<1><<<dim3(8*(rows/64)*NB), 256, 0, stream>>>(
                a, aLo, bb, bLo, Whi, Wlo, dst, dstLo, dstT, dstTLo, dstF, rows);
        else
            fusion_all_k<0><<<dim3(8*(rows/64)*NB), 256, 0, stream>>>(
                a, aLo, bb, bLo, Whi, Wlo, dst, dstLo, dstT, dstTLo, dstF, rows);
    };

    for (int l = 0; l < 2; ++l){
        const unsigned short* g_cur = (l == 0) ? g_bf0 : g_bf1;
        const unsigned short* gLoC  = (l == 0) ? gLo0  : gLo1;
        const unsigned short* c_cur = (l == 0) ? c_bf0 : c_bf1;
        const unsigned short* cLoC  = (l == 0) ? cLo0  : cLo1;
        const unsigned short* q_cur = (l == 0) ? q_bf0 : q_bf1;
        unsigned short* g_nxt = (l == 0) ? g_bf1 : g_bf0;
        unsigned short* gLoN  = (l == 0) ? gLo1  : nullptr;
        unsigned short* c_nxt = (l == 0) ? c_bf1 : c_bf0;
        unsigned short* cLoN  = (l == 0) ? cLo1  : nullptr;
        unsigned short* q_nxt = (l == 0) ? q_bf1 : q_bf0;
        float* gF = (l == 1) ? out_gloss : nullptr;
        float* cF = (l == 1) ? out_clip  : nullptr;
        float* qF = (l == 1) ? out_q     : nullptr;

        // gloss_same = adj_gc^T @ gloss  (hi/lo B, hi/lo out)
        gemmT_mfma_k<<<dim3(8, NC/64, NB), 256, 0, stream>>>(adjTgc, (size_t)NC*NG, gT, gTlo,
                                                             (size_t)512*NG, NG, NC,
                                                             agg_bf, aggLo, nullptr);
        // clip_1 (3-pass hi/lo)
        run_fusion(c_cur, cLoC, agg_bf, aggLo, NC, l, 0, 3,
                   c_nxt, cLoN, nullptr, nullptr, cF);
        // clip_agg = attn(q=gloss, kv=clip, adj_gc)
        run_attn(g_cur, NG, c_cur, NC, bm_gc, bm_cg,
                 c2gW + l*HFD, c2ga1 + l*HD, c2ga2 + l*HD, agg_bf);
        // gloss_1 (single pass; aLo still used for exact gate residual)
        run_fusion(g_cur, gLoC, agg_bf, nullptr, NG, l, 1, 1,
                   gA_bf, gALo, nullptr, nullptr, nullptr);
        // gloss_agg = attn(q=question, kv=gloss, adjT_gq)
        run_attn(q_cur, NQ, g_cur, NG, bm_qg, bm_gq,
                 g2qW + l*HFD, g2qa1 + l*HD, g2qa2 + l*HD, agg_bf);
        // question_1 (single pass)
        run_fusion(q_cur, nullptr, agg_bf, nullptr, NQ, l, 2, 1,
                   q_nxt, nullptr, nullptr, nullptr, qF);
        // question_agg = attn(q=gloss, kv=question, adj_gq)
        run_attn(g_cur, NG, q_cur, NQ, bm_gq, bm_qg,
                 q2gW + l*HFD, q2ga1 + l*HD, q2ga2 + l*HD, agg_bf);
        // gloss_2 (3-pass; emit hi/lo + transposed hi/lo for next layer's gloss_same)
        run_fusion(gA_bf, gALo, agg_bf, nullptr, NG, l, 3, 3,
                   g_nxt, gLoN, (l == 0) ? gT : nullptr, (l == 0) ? gTlo : nullptr, gF);
    }
}

// Round 5
// 699.273 us; speedup vs baseline: 1.2446x; 1.1341x over previous
//
#include <hip/hip_runtime.h>
#include <math.h>

#define NFEAT 512
#define NHEADS 8
#define HDIM 64
#define NB 4
#define NG 1024
#define NC 1024
#define NQ 256
#define NEGV -9e15f
#define CHUNKS 16
#define FF ((size_t)NFEAT*NFEAT)
#define LSTR 36   // LDS row stride (ushorts) for reg-written P tiles only
#define SEG 2304  // segmented attn rows per batch: 1024+1024+256 (k) / 1024+256+1024 (q)

typedef _Float16 v8h __attribute__((ext_vector_type(8)));
typedef float v4f __attribute__((ext_vector_type(4)));
#define MFMA16(a,b,c) __builtin_amdgcn_mfma_f32_16x16x32_f16((a),(b),(c),0,0,0)

// async global->LDS, 16B/lane, lane-linear LDS dest (wave-uniform base + lane*16)
#define GLDS(g, l) __builtin_amdgcn_global_load_lds( \
    (__attribute__((address_space(1))) void*)(g), \
    (__attribute__((address_space(3))) void*)(l), 16, 0, 0)

// XOR swizzle for 64B-row linear LDS tiles: physical 16B slot = quad ^ ((row>>1)&3).
__device__ __forceinline__ int ldsw(int row, int quad){
    return row*32 + (((quad) ^ ((row>>1)&3)) << 3);
}

__device__ __forceinline__ float lrelu(float x){ return fmaxf(x, 0.2f*x); }
__device__ __forceinline__ unsigned short f2h(float x){ union{_Float16 h; unsigned short u;} v; v.h = (_Float16)x; return v.u; }
__device__ __forceinline__ float h2f(unsigned short u){ union{_Float16 h; unsigned short u;} v; v.u = u; return (float)v.h; }

// ============ prep: fp32 -> fp16 flat ============
__global__ __launch_bounds__(256) void cvt_h_k(const float* __restrict__ src, unsigned short* __restrict__ dst){
    int idx = blockIdx.x*256 + threadIdx.x;
    const float4* s = (const float4*)(src + (size_t)idx*8);
    float4 a = s[0], b = s[1];
    ushort4 p0{f2h(a.x),f2h(a.y),f2h(a.z),f2h(a.w)};
    ushort4 p1{f2h(b.x),f2h(b.y),f2h(b.z),f2h(b.w)};
    *(ushort4*)(dst + (size_t)idx*8) = p0;
    *(ushort4*)(dst + (size_t)idx*8 + 4) = p1;
}

// ============ prep: fp32 -> fp16 hi/lo flat ============
__global__ __launch_bounds__(256) void cvt_hl_k(const float* __restrict__ src,
    unsigned short* __restrict__ dstHi, unsigned short* __restrict__ dstLo){
    int idx = blockIdx.x*256 + threadIdx.x;
    const float4* s = (const float4*)(src + (size_t)idx*8);
    float4 a = s[0], b = s[1];
    float x[8] = {a.x,a.y,a.z,a.w,b.x,b.y,b.z,b.w};
    unsigned short hi[8], lo[8];
    #pragma unroll
    for (int j = 0; j < 8; ++j){ hi[j] = f2h(x[j]); lo[j] = f2h(x[j] - h2f(hi[j])); }
    *(ushort4*)(dstHi + (size_t)idx*8)     = ushort4{hi[0],hi[1],hi[2],hi[3]};
    *(ushort4*)(dstHi + (size_t)idx*8 + 4) = ushort4{hi[4],hi[5],hi[6],hi[7]};
    *(ushort4*)(dstLo + (size_t)idx*8)     = ushort4{lo[0],lo[1],lo[2],lo[3]};
    *(ushort4*)(dstLo + (size_t)idx*8 + 4) = ushort4{lo[4],lo[5],lo[6],lo[7]};
}

// ============ prep: fusion weights -> PACKED transposed fp16 hi/lo ============
// packed layout per group li: [c0i(8)][ktI(16)][mat(4)][row64][k32]
__global__ __launch_bounds__(256) void wtT_k(const float* __restrict__ w0, const float* __restrict__ w1,
    const float* __restrict__ w2, const float* __restrict__ w3,
    unsigned short* __restrict__ dstHi, unsigned short* __restrict__ dstLo){
    int bx = blockIdx.x;
    int mat = bx >> 6, t = bx & 63;
    int a = mat & 3, li = mat >> 2;
    const float* src = (a==0?w0:a==1?w1:a==2?w2:w3) + (size_t)li*FF;
    int fo0 = (t>>3)*64, fi0 = (t&7)*64;
    __shared__ float sT[64][65];
    int tid = threadIdx.x;
    #pragma unroll
    for (int it = 0; it < 4; ++it){
        int idx = it*256 + tid;
        int r = idx >> 4, c4 = idx & 15;
        float4 v = *(const float4*)(src + (size_t)(fi0+r)*512 + fo0 + c4*4);
        sT[r][c4*4+0]=v.x; sT[r][c4*4+1]=v.y; sT[r][c4*4+2]=v.z; sT[r][c4*4+3]=v.w;
    }
    __syncthreads();
    #pragma unroll
    for (int it = 0; it < 2; ++it){
        int idx = it*256 + tid;
        int dd = idx >> 3, c8 = idx & 7;
        unsigned short hi[8], lo[8];
        #pragma unroll
        for (int j = 0; j < 8; ++j){
            float x = sT[c8*8+j][dd];
            hi[j] = f2h(x);
            lo[j] = f2h(x - h2f(hi[j]));
        }
        int ktI = (fi0 >> 5) + (c8 >> 2);
        int k31 = (c8 & 3)*8;
        size_t oo = (size_t)li*4*FF + ((((size_t)(fo0>>6)*16 + ktI)*4 + a)*64 + dd)*32 + k31;
        *(ushort4*)(dstHi+oo)   = ushort4{hi[0],hi[1],hi[2],hi[3]};
        *(ushort4*)(dstHi+oo+4) = ushort4{hi[4],hi[5],hi[6],hi[7]};
        *(ushort4*)(dstLo+oo)   = ushort4{lo[0],lo[1],lo[2],lo[3]};
        *(ushort4*)(dstLo+oo+4) = ushort4{lo[4],lo[5],lo[6],lo[7]};
    }
}

// ============ prep: 3 attn W repacks (blocks 0..191) + wa vectors (blocks 192..239) ============
__global__ __launch_bounds__(256) void prep_attnW3_k(
    const float* __restrict__ W0, const float* __restrict__ a10, const float* __restrict__ a20,
    const float* __restrict__ W1, const float* __restrict__ a11, const float* __restrict__ a21,
    const float* __restrict__ W2, const float* __restrict__ a12, const float* __restrict__ a22,
    unsigned short* __restrict__ WT3, float* __restrict__ wa13, float* __restrict__ wa23){
    int bx = blockIdx.x;
    int tid = threadIdx.x;
    if (bx >= 192){
        int r = bx - 192;
        int a = r >> 4;
        const float* W  = (a==0?W0:a==1?W1:W2);
        const float* a1 = (a==0?a10:a==1?a11:a12);
        const float* a2 = (a==0?a20:a==1?a21:a22);
        int idx = (r & 15)*256 + tid;
        int h = idx >> 9;
        const float* Wp = W + (size_t)idx*64;
        float s1 = 0.f, s2 = 0.f;
        #pragma unroll
        for (int d = 0; d < 64; ++d){ float w = Wp[d]; s1 += w*a1[(h<<6)+d]; s2 += w*a2[(h<<6)+d]; }
        wa13[a*4096 + idx] = s1; wa23[a*4096 + idx] = s2;
        return;
    }
    int a = bx >> 6, bxl = bx & 63;
    const float* W = (a==0?W0:a==1?W1:W2);
    unsigned short* WT = WT3 + (size_t)a*FF;
    int h = bxl >> 3, f0 = (bxl & 7)*64;
    __shared__ float sT[64][65];
    #pragma unroll
    for (int it = 0; it < 4; ++it){
        int idx = it*256 + tid;
        int r = idx >> 4, c4 = idx & 15;
        float4 v = *(const float4*)(W + ((size_t)h*512 + f0 + r)*64 + c4*4);
        sT[r][c4*4+0]=v.x; sT[r][c4*4+1]=v.y; sT[r][c4*4+2]=v.z; sT[r][c4*4+3]=v.w;
    }
    __syncthreads();
    #pragma unroll
    for (int it = 0; it < 2; ++it){
        int idx = it*256 + tid;
        int dd = idx >> 3, c8 = idx & 7;
        ushort4 p0{f2h(sT[c8*8+0][dd]),f2h(sT[c8*8+1][dd]),f2h(sT[c8*8+2][dd]),f2h(sT[c8*8+3][dd])};
        ushort4 p1{f2h(sT[c8*8+4][dd]),f2h(sT[c8*8+5][dd]),f2h(sT[c8*8+6][dd]),f2h(sT[c8*8+7][dd])};
        unsigned short* o = WT + ((size_t)h*64 + dd)*512 + f0 + c8*8;
        *(ushort4*)o = p0; *(ushort4*)(o+4) = p1;
    }
}

// ============ prep: adj_gc [b][g][c] int -> adjT fp16 [b][c][g] ============
__global__ __launch_bounds__(256) void adjT_h_k(const int* __restrict__ adj, unsigned short* __restrict__ dst){
    int b = blockIdx.z;
    int c0 = blockIdx.x*64, g0 = blockIdx.y*64;
    __shared__ int sI[64][65];
    int tid = threadIdx.x;
    #pragma unroll
    for (int it = 0; it < 4; ++it){
        int idx = it*256 + tid;
        int r = idx >> 4, c4 = idx & 15;
        int4 v = *(const int4*)(adj + ((size_t)b*NG + g0 + r)*NC + c0 + c4*4);
        sI[r][c4*4+0]=v.x; sI[r][c4*4+1]=v.y; sI[r][c4*4+2]=v.z; sI[r][c4*4+3]=v.w;
    }
    __syncthreads();
    #pragma unroll
    for (int it = 0; it < 2; ++it){
        int idx = it*256 + tid;
        int dd = idx >> 3, c8 = idx & 7;
        ushort4 p0, p1;
        #pragma unroll
        for (int j = 0; j < 4; ++j) (&p0.x)[j] = sI[c8*8+j][dd] > 0 ? (unsigned short)0x3C00 : (unsigned short)0;
        #pragma unroll
        for (int j = 0; j < 4; ++j) (&p1.x)[j] = sI[c8*8+4+j][dd] > 0 ? (unsigned short)0x3C00 : (unsigned short)0;
        unsigned short* o = dst + ((size_t)b*NC + c0 + dd)*NG + g0 + c8*8;
        *(ushort4*)o = p0; *(ushort4*)(o+4) = p1;
    }
}

// ============ prep: adj_gq [b][g][q] int -> adjT int [b][q][g] ============
__global__ __launch_bounds__(256) void adjT_int_k(const int* __restrict__ adj, int* __restrict__ dst){
    int b = blockIdx.z;
    int q0 = blockIdx.x*64, g0 = blockIdx.y*64;
    __shared__ int sI[64][65];
    int tid = threadIdx.x;
    #pragma unroll
    for (int it = 0; it < 4; ++it){
        int idx = it*256 + tid;
        int r = idx >> 4, c4 = idx & 15;
        int4 v = *(const int4*)(adj + ((size_t)b*NG + g0 + r)*NQ + q0 + c4*4);
        sI[r][c4*4+0]=v.x; sI[r][c4*4+1]=v.y; sI[r][c4*4+2]=v.z; sI[r][c4*4+3]=v.w;
    }
    __syncthreads();
    #pragma unroll
    for (int it = 0; it < 4; ++it){
        int idx = it*256 + tid;
        int dd = idx >> 4, c4 = idx & 15;
        int4 v{sI[c4*4+0][dd], sI[c4*4+1][dd], sI[c4*4+2][dd], sI[c4*4+3][dd]};
        *(int4*)(dst + ((size_t)b*NQ + q0 + dd)*NG + g0 + c4*4) = v;
    }
}

// ============ prep: row-ballot bitmask from int array (cols % 64 == 0) ============
__global__ __launch_bounds__(256) void bm_int_k(const int* __restrict__ adj, unsigned long long* __restrict__ out){
    int w = threadIdx.x >> 6, lane = threadIdx.x & 63;
    #pragma unroll
    for (int i = 0; i < 4; ++i){
        size_t seg = (size_t)blockIdx.x*16 + i*4 + w;
        int v = adj[seg*64 + lane];
        unsigned long long m = __ballot(v > 0);
        if (lane == 0) out[seg] = m;
    }
}

// ============ prep: row-ballot bitmask from fp16 0/1 array ============
__global__ __launch_bounds__(256) void bm_h_k(const unsigned short* __restrict__ adj, unsigned long long* __restrict__ out){
    int w = threadIdx.x >> 6, lane = threadIdx.x & 63;
    #pragma unroll
    for (int i = 0; i < 4; ++i){
        size_t seg = (size_t)blockIdx.x*16 + i*4 + w;
        unsigned short v = adj[seg*64 + lane];
        unsigned long long m = __ballot(v != 0);
        if (lane == 0) out[seg] = m;
    }
}

// ============ prep: fp32 act [b][rows][512] -> transposed hi/lo fp16 [b][512][rows] ============
__global__ __launch_bounds__(256) void actT_hl_k(const float* __restrict__ src,
    unsigned short* __restrict__ dstHi, unsigned short* __restrict__ dstLo, int Nrows){
    int b = blockIdx.z;
    int f0 = blockIdx.x*64, g0 = blockIdx.y*64;
    __shared__ float sF[64][65];
    int tid = threadIdx.x;
    #pragma unroll
    for (int it = 0; it < 4; ++it){
        int idx = it*256 + tid;
        int r = idx >> 4, c4 = idx & 15;
        float4 v = *(const float4*)(src + ((size_t)b*Nrows + g0 + r)*512 + f0 + c4*4);
        sF[r][c4*4+0]=v.x; sF[r][c4*4+1]=v.y; sF[r][c4*4+2]=v.z; sF[r][c4*4+3]=v.w;
    }
    __syncthreads();
    #pragma unroll
    for (int it = 0; it < 2; ++it){
        int idx = it*256 + tid;
        int dd = idx >> 3, c8 = idx & 7;
        unsigned short hi[8], lo[8];
        #pragma unroll
        for (int j = 0; j < 8; ++j){
            float x = sF[c8*8+j][dd];
            hi[j] = f2h(x);
            lo[j] = f2h(x - h2f(hi[j]));
        }
        size_t oo = ((size_t)b*512 + f0 + dd)*Nrows + g0 + c8*8;
        *(ushort4*)(dstHi+oo)   = ushort4{hi[0],hi[1],hi[2],hi[3]};
        *(ushort4*)(dstHi+oo+4) = ushort4{hi[4],hi[5],hi[6],hi[7]};
        *(ushort4*)(dstLo+oo)   = ushort4{lo[0],lo[1],lo[2],lo[3]};
        *(ushort4*)(dstLo+oo+4) = ushort4{lo[4],lo[5],lo[6],lo[7]};
    }
}

// ============ batched scores: all 3 attns' q and k scores in one launch ============
// qs3 segments: [0,1024)=gloss(a0) [1024,1280)=question(a1) [1280,2304)=gloss(a2)
// ks3 segments: [0,1024)=clip(a0)  [1024,2048)=gloss(a1)    [2048,2304)=question(a2)
__global__ __launch_bounds__(256) void scores3_k(
    const unsigned short* __restrict__ g, const unsigned short* __restrict__ c,
    const unsigned short* __restrict__ q,
    const float* __restrict__ wa13, const float* __restrict__ wa23,
    float* __restrict__ qs3, float* __restrict__ ks3){
    int lane = threadIdx.x & 63;
    int grow = blockIdx.x*4 + (threadIdx.x >> 6);
    int b = grow / 4608; int r = grow - b*4608;
    const unsigned short* X; const float* wa; float* out; int n, oOff, rowsX;
    if (r < SEG){
        out = qs3;
        if (r < 1024)      { X=g; wa=wa13;        n=r;        oOff=0;    rowsX=NG; }
        else if (r < 1280) { X=q; wa=wa13+4096;   n=r-1024;   oOff=1024; rowsX=NQ; }
        else               { X=g; wa=wa13+8192;   n=r-1280;   oOff=1280; rowsX=NG; }
    } else {
        out = ks3; r -= SEG;
        if (r < 1024)      { X=c; wa=wa23;        n=r;        oOff=0;    rowsX=NC; }
        else if (r < 2048) { X=g; wa=wa23+4096;   n=r-1024;   oOff=1024; rowsX=NG; }
        else               { X=q; wa=wa23+8192;   n=r-2048;   oOff=2048; rowsX=NQ; }
    }
    const unsigned short* Xr = X + ((size_t)b*rowsX + n)*NFEAT;
    float p[NHEADS];
    #pragma unroll
    for (int h = 0; h < NHEADS; ++h) p[h] = 0.f;
    #pragma unroll
    for (int cc = 0; cc < 8; ++cc){
        float x = h2f(Xr[(cc<<6) + lane]);
        #pragma unroll
        for (int h = 0; h < NHEADS; ++h) p[h] += x * wa[(h<<9) + (cc<<6) + lane];
    }
    #pragma unroll
    for (int h = 0; h < NHEADS; ++h){
        float v = p[h];
        #pragma unroll
        for (int off = 32; off > 0; off >>= 1) v += __shfl_xor(v, off);
        if (lane == 0) out[((size_t)b*SEG + oOff + n)*8 + h] = v;
    }
}

// ============ batched WkT gemm: WkT3[b][512][2304] = {clip,gloss,question} @ WT3[a]^T ============
__global__ __launch_bounds__(256) void wkt3_mfma_k(
    const unsigned short* __restrict__ c, const unsigned short* __restrict__ g,
    const unsigned short* __restrict__ q, const unsigned short* __restrict__ WT3,
    unsigned short* __restrict__ WkT3){
    int b = blockIdx.z;
    int y = blockIdx.y;
    const unsigned short* kv; int rowsX, mOff, a;
    if (y < 16)      { a=0; kv=c; rowsX=NC; mOff=0; }
    else if (y < 32) { a=1; y-=16; kv=g; rowsX=NG; mOff=1024; }
    else             { a=2; y-=32; kv=q; rowsX=NQ; mOff=2048; }
    int r0 = y*64, c0 = blockIdx.x*64;
    int tid = threadIdx.x;
    __shared__ alignas(16) unsigned short aS[2][2048], bS[2][2048];
    const unsigned short* aG = kv + (size_t)b*rowsX*512;
    const unsigned short* bG = WT3 + (size_t)a*FF;
    int w = tid >> 6, lane = tid & 63;
    int lrow = lane & 15, quad = lane >> 4;
    int sr = tid >> 2;
    int sq = (tid & 3) ^ ((sr >> 1) & 3);
    size_t aRow = (size_t)(r0 + sr)*512 + sq*8;
    size_t bRow = (size_t)(c0 + sr)*512 + sq*8;
    v4f acc[4];
    #pragma unroll
    for (int cf = 0; cf < 4; ++cf) acc[cf] = (v4f)0.f;
    GLDS(aG + aRow, &aS[0][w << 9]);
    GLDS(bG + bRow, &bS[0][w << 9]);
    __syncthreads();
    int buf = 0;
    for (int s = 0; s < 16; ++s){
        if (s < 15){
            int ktn = (s + 1) << 5;
            GLDS(aG + aRow + ktn, &aS[buf^1][w << 9]);
            GLDS(bG + bRow + ktn, &bS[buf^1][w << 9]);
        }
        v8h af = *(const v8h*)&aS[buf][ldsw(w*16 + lrow, quad)];
        #pragma unroll
        for (int cf = 0; cf < 4; ++cf){
            v8h bf = *(const v8h*)&bS[buf][ldsw(cf*16 + lrow, quad)];
            acc[cf] = MFMA16(af, bf, acc[cf]);
        }
        __syncthreads();
        buf ^= 1;
    }
    #pragma unroll
    for (int cf = 0; cf < 4; ++cf){
        int colg = c0 + cf*16 + lrow;
        int rbase = r0 + w*16 + quad*4;
        ushort4 pk{f2h(acc[cf][0]), f2h(acc[cf][1]), f2h(acc[cf][2]), f2h(acc[cf][3])};
        *(ushort4*)&WkT3[((size_t)b*512 + colg)*SEG + mOff + rbase] = pk;
    }
}

// ============ batched colstat: all 3 attns, per-chunk (cm, sum) via bitmasks ============
__global__ __launch_bounds__(256) void colstat3_k(
    const unsigned* __restrict__ bm_cg, const unsigned* __restrict__ bm_gq,
    const unsigned* __restrict__ bm_qg,
    const float* __restrict__ qs3, const float* __restrict__ ks3,
    float* __restrict__ pcm, float* __restrict__ psum){
    int x = blockIdx.x, b = blockIdx.z;
    const unsigned* bm; int Mrows, N, N32, mOff, qOff;
    if (x < 256)      { bm=bm_cg; Mrows=NC; N=NG; N32=NG/32; mOff=0;    qOff=0; }
    else if (x < 512) { x-=256; bm=bm_gq; Mrows=NG; N=NQ; N32=NQ/32; mOff=1024; qOff=1024; }
    else              { x-=512; bm=bm_qg; Mrows=NQ; N=NG; N32=NG/32; mOff=2048; qOff=1280; }
    int mt = x >> 4, ch = x & 15;
    int chunk = N / CHUNKS, subl = chunk >> 2;
    int ml = threadIdx.x & 63; int m = mt*64 + ml;
    int g = threadIdx.x >> 6;
    int n0 = ch*chunk + g*subl;
    __shared__ float sQ[64][8];
    for (int t2 = threadIdx.x; t2 < chunk*8; t2 += 256)
        sQ[t2>>3][t2&7] = qs3[((size_t)b*SEG + qOff + ch*chunk)*8 + t2];
    float ksv[8];
    size_t mo = ((size_t)b*SEG + mOff + m)*8;
    #pragma unroll
    for (int h = 0; h < 8; ++h) ksv[h] = ks3[mo+h];
    unsigned word = bm[((size_t)b*Mrows + m)*N32 + (n0>>5)];
    unsigned bits = (word >> (n0 & 31)) & ((1u << subl) - 1u);
    __syncthreads();
    int nb = g*subl;
    float mx[8];
    #pragma unroll
    for (int h = 0; h < 8; ++h) mx[h] = -INFINITY;
    for (int i = 0; i < subl; ++i){
        if ((bits >> i) & 1){
            #pragma unroll
            for (int h = 0; h < 8; ++h) mx[h] = fmaxf(mx[h], sQ[nb+i][h]);
        }
    }
    float cm[8], s[8];
    #pragma unroll
    for (int h = 0; h < 8; ++h){
        cm[h] = bits ? lrelu(mx[h] + ksv[h]) : NEGV;
        s[h] = 0.f;
    }
    for (int i = 0; i < subl; ++i){
        bool on = (bits >> i) & 1;
        #pragma unroll
        for (int h = 0; h < 8; ++h){
            float e = on ? lrelu(sQ[nb+i][h] + ksv[h]) : NEGV;
            s[h] += __expf(e - cm[h]);
        }
    }
    __shared__ float scm[4][64][8], ssm[4][64][8];
    #pragma unroll
    for (int h = 0; h < 8; ++h){ scm[g][ml][h] = cm[h]; ssm[g][ml][h] = s[h]; }
    __syncthreads();
    if (g == 0){
        #pragma unroll
        for (int h = 0; h < 8; ++h){
            float c0 = scm[0][ml][h], c1 = scm[1][ml][h], c2 = scm[2][ml][h], c3 = scm[3][ml][h];
            float CM = fmaxf(fmaxf(c0, c1), fmaxf(c2, c3));
            float S = ssm[0][ml][h]*__expf(c0-CM) + ssm[1][ml][h]*__expf(c1-CM)
                    + ssm[2][ml][h]*__expf(c2-CM) + ssm[3][ml][h]*__expf(c3-CM);
            size_t o = (((size_t)b*CHUNKS + ch)*SEG + mOff + m)*8 + h;
            pcm[o] = CM; psum[o] = S;
        }
    }
}

// ============ batched finalize: chunk-combine + repack -> ksh/cmh/ish [b][8][SEG] ============
__global__ __launch_bounds__(256) void colfin3_k(const float* __restrict__ pcm, const float* __restrict__ psum,
    const float* __restrict__ ks3, float* __restrict__ ksh, float* __restrict__ cmh,
    float* __restrict__ ish){
    int idx = blockIdx.x*256 + threadIdx.x;    // NB*SEG*8
    const int m8 = SEG*8;
    int b = idx / m8, rem = idx - b*m8;
    int m = rem >> 3, h = rem & 7;
    size_t base = (size_t)b*CHUNKS*m8 + rem;
    float c[CHUNKS], s[CHUNKS];
    #pragma unroll
    for (int ch = 0; ch < CHUNKS; ++ch){
        c[ch] = pcm[base + (size_t)ch*m8];
        s[ch] = psum[base + (size_t)ch*m8];
    }
    float CM = c[0];
    #pragma unroll
    for (int ch = 1; ch < CHUNKS; ++ch) CM = fmaxf(CM, c[ch]);
    float S = 0.f;
    #pragma unroll
    for (int ch = 0; ch < CHUNKS; ++ch) S += s[ch]*__expf(c[ch] - CM);
    size_t o = ((size_t)b*8 + h)*SEG + m;
    ksh[o] = ks3[idx]; cmh[o] = CM; ish[o] = 1.f/S;
}

// ============ fused fusion MFMA: 64x64 tile, packed weights, GLDS staging ============
template<int MULTI>
__global__ __launch_bounds__(256) void fusion_all_k(
    const unsigned short* __restrict__ aHi, const unsigned short* __restrict__ aLo,
    const unsigned short* __restrict__ bHi, const unsigned short* __restrict__ bLo,
    const unsigned short* __restrict__ Whi, const unsigned short* __restrict__ Wlo,
    unsigned short* __restrict__ dst, unsigned short* __restrict__ dstLo,
    unsigned short* __restrict__ dstT, unsigned short* __restrict__ dstTLo,
    float* __restrict__ dstF, int rows){
    int nY = rows >> 6;
    int ppg = (nY * NB) >> 3;
    int F = blockIdx.x;
    int xcd = F & 7, t = F >> 3;
    int c0i = t / ppg;
    int p = xcd + ((t - c0i*ppg) << 3);
    int r0 = (p % nY) << 6, c0 = c0i << 6;
    int b = p / nY;
    int tid = threadIdx.x;
    __shared__ alignas(16) unsigned short aHs[2048], bHs[2048];
    __shared__ alignas(16) unsigned short aLs[MULTI ? 2048 : 16], bLs[MULTI ? 2048 : 16];
    __shared__ alignas(16) unsigned short wHs[8192];
    __shared__ alignas(16) unsigned short wLs[MULTI ? 8192 : 16];
    size_t actOff = (size_t)b*rows*512;
    const unsigned short* aHG = aHi + actOff;
    const unsigned short* bHG = bHi + actOff;
    const unsigned short* aLG = aLo ? aLo + actOff : nullptr;
    const unsigned short* bLG = bLo ? bLo + actOff : nullptr;
    bool hasALo = MULTI && (aLG != nullptr);
    bool hasBLo = MULTI && (bLG != nullptr);
    int w = tid >> 6, lane = tid & 63;
    int wr = w >> 1, wc = w & 1;
    int lrow = lane & 15, quad = lane >> 4;
    int sr = tid >> 2;
    int sq = (tid & 3) ^ ((sr >> 1) & 3);
    size_t aRow = (size_t)(r0 + sr)*512 + sq*8;
    size_t wPk = (size_t)c0i*16*8192 + (size_t)sr*32 + sq*8;
    unsigned short* ldsA  = &aHs[w << 9];
    unsigned short* ldsB  = &bHs[w << 9];
    unsigned short* ldsAL = &aLs[MULTI ? (w << 9) : 0];
    unsigned short* ldsBL = &bLs[MULTI ? (w << 9) : 0];
    v4f accN[2][2], accF[2][2];
    #pragma unroll
    for (int r = 0; r < 2; ++r)
        #pragma unroll
        for (int cf = 0; cf < 2; ++cf){ accN[r][cf] = (v4f)0.f; accF[r][cf] = (v4f)0.f; }
    for (int kt = 0; kt < 512; kt += 32){
        __syncthreads();
        GLDS(aHG + aRow + kt, ldsA);
        GLDS(bHG + aRow + kt, ldsB);
        if (hasALo) GLDS(aLG + aRow + kt, ldsAL);
        if (hasBLo) GLDS(bLG + aRow + kt, ldsBL);
        size_t wk = wPk + (size_t)(kt >> 5)*8192;
        #pragma unroll
        for (int m = 0; m < 4; ++m){
            GLDS(Whi + wk + (m<<11), &wHs[(m<<11) + (w<<9)]);
            if (MULTI) GLDS(Wlo + wk + (m<<11), &wLs[MULTI ? ((m<<11) + (w<<9)) : 0]);
        }
        __syncthreads();
        v8h ah[2], bh[2], al[2], bl[2];
        #pragma unroll
        for (int r = 0; r < 2; ++r){
            int ao = ldsw(wr*32 + r*16 + lrow, quad);
            ah[r] = *(const v8h*)&aHs[ao];
            bh[r] = *(const v8h*)&bHs[ao];
            if (hasALo) al[r] = *(const v8h*)&aLs[ao];
            if (hasBLo) bl[r] = *(const v8h*)&bLs[ao];
        }
        #pragma unroll
        for (int cf = 0; cf < 2; ++cf){
            int wo = ldsw(wc*32 + cf*16 + lrow, quad);
            v8h w0 = *(const v8h*)&wHs[wo];
            v8h w1 = *(const v8h*)&wHs[2048 + wo];
            v8h w2 = *(const v8h*)&wHs[4096 + wo];
            v8h w3 = *(const v8h*)&wHs[6144 + wo];
            v8h l0, l1, l2, l3;
            if (MULTI){
                l0 = *(const v8h*)&wLs[wo];
                l1 = *(const v8h*)&wLs[2048 + wo];
                l2 = *(const v8h*)&wLs[4096 + wo];
                l3 = *(const v8h*)&wLs[6144 + wo];
            }
            #pragma unroll
            for (int r = 0; r < 2; ++r){
                accN[r][cf] = MFMA16(ah[r], w0, accN[r][cf]);
                accN[r][cf] = MFMA16(bh[r], w1, accN[r][cf]);
                accF[r][cf] = MFMA16(ah[r], w2, accF[r][cf]);
                accF[r][cf] = MFMA16(bh[r], w3, accF[r][cf]);
                if (MULTI){
                    if (hasALo){ accN[r][cf] = MFMA16(al[r], w0, accN[r][cf]); accF[r][cf] = MFMA16(al[r], w2, accF[r][cf]); }
                    if (hasBLo){ accN[r][cf] = MFMA16(bl[r], w1, accN[r][cf]); accF[r][cf] = MFMA16(bl[r], w3, accF[r][cf]); }
                    accN[r][cf] = MFMA16(ah[r], l0, accN[r][cf]);
                    accN[r][cf] = MFMA16(bh[r], l1, accN[r][cf]);
                    accF[r][cf] = MFMA16(ah[r], l2, accF[r][cf]);
                    accF[r][cf] = MFMA16(bh[r], l3, accF[r][cf]);
                }
            }
        }
    }
    #pragma unroll
    for (int r = 0; r < 2; ++r)
        #pragma unroll
        for (int cf = 0; cf < 2; ++cf){
            int colg = c0 + wc*32 + cf*16 + lrow;
            int rbase = r0 + wr*32 + r*16 + quad*4;
            float o4[4];
            #pragma unroll
            for (int reg = 0; reg < 4; ++reg){
                float f = 1.f/(1.f + __expf(-accF[r][cf][reg]));
                size_t ai = (size_t)(rbase+reg)*512 + colg;
                float ao = h2f(aHG[ai]);
                if (aLG) ao += h2f(aLG[ai]);
                o4[reg] = f*accN[r][cf][reg] + (1.f - f)*ao;
                size_t oo = ((size_t)b*rows + rbase + reg)*512 + colg;
                unsigned short hv = f2h(o4[reg]);
                dst[oo] = hv;
                if (dstLo) dstLo[oo] = f2h(o4[reg] - h2f(hv));
                if (dstF) dstF[oo] = o4[reg];
            }
            if (dstT){
                unsigned short h0 = f2h(o4[0]), h1 = f2h(o4[1]), h2 = f2h(o4[2]), h3 = f2h(o4[3]);
                size_t to = ((size_t)b*512 + colg)*rows + rbase;
                *(ushort4*)&dstT[to] = ushort4{h0,h1,h2,h3};
                if (dstTLo)
                    *(ushort4*)&dstTLo[to] = ushort4{f2h(o4[0]-h2f(h0)), f2h(o4[1]-h2f(h1)),
                                                     f2h(o4[2]-h2f(h2)), f2h(o4[3]-h2f(h3))};
            }
        }
}

// ============ generic MFMA GEMM (64-row tiles, double-buffered) — gloss_same only ============
__global__ __launch_bounds__(256) void gemmT_mfma_k(
    const unsigned short* __restrict__ A, size_t aStride,
    const unsigned short* __restrict__ BT, const unsigned short* __restrict__ BT2, size_t bStride,
    int K, int rowsPB,
    unsigned short* __restrict__ outRM, unsigned short* __restrict__ outLo,
    unsigned short* __restrict__ outT){
    int b = blockIdx.z;
    int r0 = blockIdx.y*64, c0 = blockIdx.x*64;
    int tid = threadIdx.x;
    __shared__ alignas(16) unsigned short aS[2][2048], bS[2][2048];
    const unsigned short* aG = A + (size_t)b*aStride;
    const unsigned short* bG0 = BT + (size_t)b*bStride;
    const unsigned short* bG1 = BT2 ? BT2 + (size_t)b*bStride : nullptr;
    int w = tid >> 6, lane = tid & 63;
    int lrow = lane & 15, quad = lane >> 4;
    int sr = tid >> 2;
    int sq = (tid & 3) ^ ((sr >> 1) & 3);
    size_t aRow = (size_t)(r0 + sr)*K + sq*8;
    size_t bRow = (size_t)(c0 + sr)*K + sq*8;
    int spp = K >> 5;
    int nsteps = (BT2 ? 2 : 1)*spp;
    v4f acc[4];
    #pragma unroll
    for (int cf = 0; cf < 4; ++cf) acc[cf] = (v4f)0.f;
    GLDS(aG + aRow, &aS[0][w << 9]);
    GLDS(bG0 + bRow, &bS[0][w << 9]);
    __syncthreads();
    int buf = 0;
    for (int s = 0; s < nsteps; ++s){
        int sn = s + 1;
        if (sn < nsteps){
            int ktn = ((sn >= spp) ? (sn - spp) : sn) << 5;
            const unsigned short* bgn = (sn >= spp) ? bG1 : bG0;
            GLDS(aG + aRow + ktn, &aS[buf^1][w << 9]);
            GLDS(bgn + bRow + ktn, &bS[buf^1][w << 9]);
        }
        v8h af = *(const v8h*)&aS[buf][ldsw(w*16 + lrow, quad)];
        #pragma unroll
        for (int cf = 0; cf < 4; ++cf){
            v8h bf = *(const v8h*)&bS[buf][ldsw(cf*16 + lrow, quad)];
            acc[cf] = MFMA16(af, bf, acc[cf]);
        }
        __syncthreads();
        buf ^= 1;
    }
    #pragma unroll
    for (int cf = 0; cf < 4; ++cf){
        int colg = c0 + cf*16 + lrow;
        int rbase = r0 + w*16 + quad*4;
        if (outRM){
            #pragma unroll
            for (int reg = 0; reg < 4; ++reg){
                float v = acc[cf][reg];
                unsigned short hv = f2h(v);
                size_t oo = ((size_t)b*rowsPB + rbase + reg)*512 + colg;
                outRM[oo] = hv;
                if (outLo) outLo[oo] = f2h(v - h2f(hv));
            }
        }
        if (outT){
            ushort4 pk{f2h(acc[cf][0]), f2h(acc[cf][1]), f2h(acc[cf][2]), f2h(acc[cf][3])};
            *(ushort4*)&outT[((size_t)b*512 + colg)*rowsPB + rbase] = pk;
        }
    }
}

// ============ attention output MFMA: T1-swizzled grid, LDS stats, bitmask adj ============
__global__ __launch_bounds__(256) void attn_mfma_k(const unsigned* __restrict__ bmN, int M32,
    const float* __restrict__ qs3, int qOff,
    const float* __restrict__ ksh, const float* __restrict__ cmh, const float* __restrict__ ish,
    int mOff, const unsigned short* __restrict__ WkT3,
    unsigned short* __restrict__ outp, int N, int M){
    // T1: nN0 blocks of same (b,h) on one XCD
    int nN0 = N >> 6;
    int F = blockIdx.x;
    int xcd = F & 7, t = F >> 3;
    int bh = xcd*4 + t/nN0;
    int n0 = (t % nN0) << 6;
    int b = bh >> 3, h = bh & 7;
    int tid = threadIdx.x;
    __shared__ unsigned short pS[2*64*LSTR];
    __shared__ alignas(16) unsigned short wS[2*2048];
    __shared__ float qsS[64];
    __shared__ alignas(16) float sKs[1024], sCm[1024], sIs[1024];
    const float* ksb = ksh + ((size_t)b*8 + h)*SEG + mOff;
    const float* cmb = cmh + ((size_t)b*8 + h)*SEG + mOff;
    const float* isb = ish + ((size_t)b*8 + h)*SEG + mOff;
    const unsigned short* wkb = WkT3 + ((size_t)b*512 + h*64)*SEG + mOff;
    int w = tid >> 6, lane = tid & 63;
    int lrow = lane & 15, quad = lane >> 4;
    int pn = tid >> 2, pm = (tid & 3)*8;
    int sr = tid >> 2;
    int sq = (tid & 3) ^ ((sr >> 1) & 3);
    // stage stats to LDS (16B/lane GLDS)
    for (int o = w*256; o < M; o += 1024){
        GLDS(ksb + o + lane*4, &sKs[o]);
        GLDS(cmb + o + lane*4, &sCm[o]);
        GLDS(isb + o + lane*4, &sIs[o]);
    }
    if (tid < 64) qsS[tid] = qs3[((size_t)b*SEG + qOff + n0 + tid)*8 + h];
    const unsigned* bmrow = bmN + ((size_t)b*N + n0 + pn)*M32;
    v4f acc[4];
    #pragma unroll
    for (int cf = 0; cf < 4; ++cf) acc[cf] = (v4f)0.f;
    uint2 CW = *(const uint2*)(bmrow);
    uint2 NW;
    __syncthreads();          // qsS + stats visible
    float qv = qsS[pn];
    for (int mt = 0; mt < M; mt += 64){
        int mtB = mt + 32;
        int mtN = (mt + 64 < M) ? (mt + 64) : 0;
        // ---- sub-step 0 ----
        GLDS(wkb + (size_t)sr*SEG + mt + sq*8, &wS[w << 9]);
        {
            unsigned bb = (CW.x >> pm) & 0xffu;
            float4 k0 = *(const float4*)&sKs[mt+pm], k1 = *(const float4*)&sKs[mt+pm+4];
            float4 c0 = *(const float4*)&sCm[mt+pm], c1 = *(const float4*)&sCm[mt+pm+4];
            float4 i0 = *(const float4*)&sIs[mt+pm], i1 = *(const float4*)&sIs[mt+pm+4];
            float p[8];
            const float* kk0 = &k0.x; const float* kk1 = &k1.x;
            const float* cc0 = &c0.x; const float* cc1 = &c1.x;
            const float* ii0 = &i0.x; const float* ii1 = &i1.x;
            #pragma unroll
            for (int j = 0; j < 4; ++j){
                float e = ((bb >> j) & 1) ? lrelu(qv + kk0[j]) : NEGV;
                p[j] = __expf(e - cc0[j]) * ii0[j];
            }
            #pragma unroll
            for (int j = 0; j < 4; ++j){
                float e = ((bb >> (4+j)) & 1) ? lrelu(qv + kk1[j]) : NEGV;
                p[4+j] = __expf(e - cc1[j]) * ii1[j];
            }
            *(ushort4*)&pS[pn*LSTR + pm]     = ushort4{f2h(p[0]), f2h(p[1]), f2h(p[2]), f2h(p[3])};
            *(ushort4*)&pS[pn*LSTR + pm + 4] = ushort4{f2h(p[4]), f2h(p[5]), f2h(p[6]), f2h(p[7])};
        }
        __syncthreads();
        {
            v8h af = *(const v8h*)&pS[(w*16 + lrow)*LSTR + quad*8];
            #pragma unroll
            for (int cf = 0; cf < 4; ++cf){
                v8h bf = *(const v8h*)&wS[ldsw(cf*16 + lrow, quad)];
                acc[cf] = MFMA16(af, bf, acc[cf]);
            }
        }
        // ---- sub-step 1 ----
        GLDS(wkb + (size_t)sr*SEG + mtB + sq*8, &wS[2048 + (w << 9)]);
        NW = *(const uint2*)(bmrow + (mtN >> 5));
        {
            unsigned bb = (CW.y >> pm) & 0xffu;
            float4 k0 = *(const float4*)&sKs[mtB+pm], k1 = *(const float4*)&sKs[mtB+pm+4];
            float4 c0 = *(const float4*)&sCm[mtB+pm], c1 = *(const float4*)&sCm[mtB+pm+4];
            float4 i0 = *(const float4*)&sIs[mtB+pm], i1 = *(const float4*)&sIs[mtB+pm+4];
            float p[8];
            const float* kk0 = &k0.x; const float* kk1 = &k1.x;
            const float* cc0 = &c0.x; const float* cc1 = &c1.x;
            const float* ii0 = &i0.x; const float* ii1 = &i1.x;
            #pragma unroll
            for (int j = 0; j < 4; ++j){
                float e = ((bb >> j) & 1) ? lrelu(qv + kk0[j]) : NEGV;
                p[j] = __expf(e - cc0[j]) * ii0[j];
            }
            #pragma unroll
            for (int j = 0; j < 4; ++j){
                float e = ((bb >> (4+j)) & 1) ? lrelu(qv + kk1[j]) : NEGV;
                p[4+j] = __expf(e - cc1[j]) * ii1[j];
            }
            *(ushort4*)&pS[2304 + pn*LSTR + pm]     = ushort4{f2h(p[0]), f2h(p[1]), f2h(p[2]), f2h(p[3])};
            *(ushort4*)&pS[2304 + pn*LSTR + pm + 4] = ushort4{f2h(p[4]), f2h(p[5]), f2h(p[6]), f2h(p[7])};
        }
        __syncthreads();
        {
            v8h af = *(const v8h*)&pS[2304 + (w*16 + lrow)*LSTR + quad*8];
            #pragma unroll
            for (int cf = 0; cf < 4; ++cf){
                v8h bf = *(const v8h*)&wS[2048 + ldsw(cf*16 + lrow, quad)];
                acc[cf] = MFMA16(af, bf, acc[cf]);
            }
        }
        CW = NW;
    }
    #pragma unroll
    for (int cf = 0; cf < 4; ++cf){
        int colg = h*64 + cf*16 + lrow;
        int rbase = n0 + w*16 + quad*4;
        #pragma unroll
        for (int reg = 0; reg < 4; ++reg){
            float v = acc[cf][reg];
            v = (v > 0.f) ? v : (__expf(v) - 1.f);
            outp[((size_t)b*N + rbase + reg)*512 + colg] = f2h(v);
        }
    }
}

extern "C" void kernel_launch(void* const* d_in, const int* in_sizes, int n_in,
                              void* d_out, int out_size, void* d_ws, size_t ws_size,
                              hipStream_t stream){
    const float* in_gloss = (const float*)d_in[0];
    const float* in_clip  = (const float*)d_in[1];
    const float* in_q     = (const float*)d_in[2];
    const int*   adj_gc   = (const int*)d_in[3];
    const int*   adj_gq   = (const int*)d_in[4];
    const float* c2gW  = (const float*)d_in[5];
    const float* c2ga1 = (const float*)d_in[6];
    const float* c2ga2 = (const float*)d_in[7];
    const float* g2qW  = (const float*)d_in[8];
    const float* g2qa1 = (const float*)d_in[9];
    const float* g2qa2 = (const float*)d_in[10];
    const float* q2gW  = (const float*)d_in[11];
    const float* q2ga1 = (const float*)d_in[12];
    const float* q2ga2 = (const float*)d_in[13];
    const float* fusW  = (const float*)d_in[14];
    const float* fusU  = (const float*)d_in[15];
    const float* fusWf = (const float*)d_in[16];
    const float* fusUf = (const float*)d_in[17];
    float* out = (float*)d_out;
    float* out_gloss = out;
    float* out_clip  = out + (size_t)NB*NG*NFEAT;
    float* out_q     = out + (size_t)NB*NG*NFEAT*2;

    char* wsB = (char*)d_ws;
    size_t off = 0;
    auto alloc = [&](size_t bytes){ void* p = wsB + off; off += (bytes + 255) & ~(size_t)255; return p; };
    float* wa13  = (float*)alloc(3*4096*4);
    float* wa23  = (float*)alloc(3*4096*4);
    float* qs3   = (float*)alloc((size_t)NB*SEG*8*4);
    float* ks3   = (float*)alloc((size_t)NB*SEG*8*4);
    float* ksh3  = (float*)alloc((size_t)NB*8*SEG*4);
    float* cmh3  = (float*)alloc((size_t)NB*8*SEG*4);
    float* ish3  = (float*)alloc((size_t)NB*8*SEG*4);
    float* pcm   = (float*)alloc((size_t)NB*CHUNKS*SEG*8*4);
    float* psum  = (float*)alloc((size_t)NB*CHUNKS*SEG*8*4);
    unsigned short* WflatT3 = (unsigned short*)alloc((size_t)3*FF*2);
    unsigned short* WkT3    = (unsigned short*)alloc((size_t)NB*512*SEG*2);
    unsigned short* wtAll   = (unsigned short*)alloc((size_t)32*FF*2);
    unsigned short* wtAllLo = (unsigned short*)alloc((size_t)32*FF*2);
    unsigned short* adjTgc  = (unsigned short*)alloc((size_t)NB*NC*NG*2);
    unsigned short* g_bf0   = (unsigned short*)alloc((size_t)NB*NG*NFEAT*2);
    unsigned short* gLo0    = (unsigned short*)alloc((size_t)NB*NG*NFEAT*2);
    unsigned short* g_bf1   = (unsigned short*)alloc((size_t)NB*NG*NFEAT*2);
    unsigned short* gLo1    = (unsigned short*)alloc((size_t)NB*NG*NFEAT*2);
    unsigned short* gT      = (unsigned short*)alloc((size_t)NB*NFEAT*NG*2);
    unsigned short* gTlo    = (unsigned short*)alloc((size_t)NB*NFEAT*NG*2);
    unsigned short* gA_bf   = (unsigned short*)alloc((size_t)NB*NG*NFEAT*2);
    unsigned short* gALo    = (unsigned short*)alloc((size_t)NB*NG*NFEAT*2);
    unsigned short* c_bf0   = (unsigned short*)alloc((size_t)NB*NC*NFEAT*2);
    unsigned short* cLo0    = (unsigned short*)alloc((size_t)NB*NC*NFEAT*2);
    unsigned short* c_bf1   = (unsigned short*)alloc((size_t)NB*NC*NFEAT*2);
    unsigned short* cLo1    = (unsigned short*)alloc((size_t)NB*NC*NFEAT*2);
    unsigned short* q_bf0   = (unsigned short*)alloc((size_t)NB*NQ*NFEAT*2);
    unsigned short* q_bf1   = (unsigned short*)alloc((size_t)NB*NQ*NFEAT*2);
    unsigned short* agg_bf  = (unsigned short*)alloc((size_t)NB*NG*NFEAT*2);
    unsigned short* aggLo   = (unsigned short*)alloc((size_t)NB*NG*NFEAT*2);
    int* adjTgq = (int*)alloc((size_t)NB*NQ*NG*4);
    unsigned* bm_gc = (unsigned*)alloc((size_t)NB*NG*(NC/32)*4);
    unsigned* bm_cg = (unsigned*)alloc((size_t)NB*NC*(NG/32)*4);
    unsigned* bm_gq = (unsigned*)alloc((size_t)NB*NG*(NQ/32)*4);
    unsigned* bm_qg = (unsigned*)alloc((size_t)NB*NQ*(NG/32)*4);
    (void)ws_size; (void)in_sizes; (void)n_in; (void)out_size;

    const size_t HFD = (size_t)NHEADS*NFEAT*HDIM;
    const size_t HD  = (size_t)NHEADS*HDIM;

    // ---- prep ----
    wtT_k<<<2048, 256, 0, stream>>>(fusW, fusU, fusWf, fusUf, wtAll, wtAllLo);
    adjT_h_k<<<dim3(NC/64, NG/64, NB), 256, 0, stream>>>(adj_gc, adjTgc);
    adjT_int_k<<<dim3(NQ/64, NG/64, NB), 256, 0, stream>>>(adj_gq, adjTgq);
    bm_int_k<<<(NB*NG*NC/64)/16, 256, 0, stream>>>(adj_gc, (unsigned long long*)bm_gc);
    bm_int_k<<<(NB*NG*NQ/64)/16, 256, 0, stream>>>(adj_gq, (unsigned long long*)bm_gq);
    bm_int_k<<<(NB*NQ*NG/64)/16, 256, 0, stream>>>(adjTgq, (unsigned long long*)bm_qg);
    bm_h_k<<<(NB*NC*NG/64)/16, 256, 0, stream>>>(adjTgc, (unsigned long long*)bm_cg);
    cvt_hl_k<<<(NB*NG*NFEAT)/2048, 256, 0, stream>>>(in_gloss, g_bf0, gLo0);
    cvt_hl_k<<<(NB*NC*NFEAT)/2048, 256, 0, stream>>>(in_clip,  c_bf0, cLo0);
    cvt_h_k<<<(NB*NQ*NFEAT)/2048, 256, 0, stream>>>(in_q,     q_bf0);
    actT_hl_k<<<dim3(8, NG/64, NB), 256, 0, stream>>>(in_gloss, gT, gTlo, NG);

    auto run_fusion = [&](const unsigned short* a, const unsigned short* aLo,
                          const unsigned short* bb, const unsigned short* bLo, int rows,
                          int l, int i, int npass,
                          unsigned short* dst, unsigned short* dstLo,
                          unsigned short* dstT, unsigned short* dstTLo, float* dstF){
        const unsigned short* Whi = wtAll   + (size_t)((l*4 + i)*4)*FF;
        const unsigned short* Wlo = wtAllLo + (size_t)((l*4 + i)*4)*FF;
        if (npass == 3)
            fusion_all_k<1><<<dim3(8*(rows/64)*NB), 256, 0, stream>>>(
                a, aLo, bb, bLo, Whi, Wlo, dst, dstLo, dstT, dstTLo, dstF, rows);
        else
            fusion_all_k<0><<<dim3(8*(rows/64)*NB), 256, 0, stream>>>(
                a, aLo, bb, bLo, Whi, Wlo, dst, dstLo, dstT, dstTLo, dstF, rows);
    };

    for (int l = 0; l < 2; ++l){
        const unsigned short* g_cur = (l == 0) ? g_bf0 : g_bf1;
        const unsigned short* gLoC  = (l == 0) ? gLo0  : gLo1;
        const unsigned short* c_cur = (l == 0) ? c_bf0 : c_bf1;
        const unsigned short* cLoC  = (l == 0) ? cLo0  : cLo1;
        const unsigned short* q_cur = (l == 0) ? q_bf0 : q_bf1;
        unsigned short* g_nxt = (l == 0) ? g_bf1 : g_bf0;
        unsigned short* gLoN  = (l == 0) ? gLo1  : nullptr;
        unsigned short* c_nxt = (l == 0) ? c_bf1 : c_bf0;
        unsigned short* cLoN  = (l == 0) ? cLo1  : nullptr;
        unsigned short* q_nxt = (l == 0) ? q_bf1 : q_bf0;
        float* gF = (l == 1) ? out_gloss : nullptr;
        float* cF = (l == 1) ? out_clip  : nullptr;
        float* qF = (l == 1) ? out_q     : nullptr;

        // ---- batched attention prep (depends only on layer inputs) ----
        prep_attnW3_k<<<240, 256, 0, stream>>>(
            c2gW + l*HFD, c2ga1 + l*HD, c2ga2 + l*HD,
            g2qW + l*HFD, g2qa1 + l*HD, g2qa2 + l*HD,
            q2gW + l*HFD, q2ga1 + l*HD, q2ga2 + l*HD,
            WflatT3, wa13, wa23);
        scores3_k<<<(NB*4608)/4, 256, 0, stream>>>(g_cur, c_cur, q_cur, wa13, wa23, qs3, ks3);
        wkt3_mfma_k<<<dim3(8, 36, NB), 256, 0, stream>>>(c_cur, g_cur, q_cur, WflatT3, WkT3);
        colstat3_k<<<dim3(576, 1, NB), 256, 0, stream>>>(bm_cg, bm_gq, bm_qg, qs3, ks3, pcm, psum);
        colfin3_k<<<(NB*SEG*8)/256, 256, 0, stream>>>(pcm, psum, ks3, ksh3, cmh3, ish3);

        // gloss_same = adj_gc^T @ gloss  (hi/lo B, hi/lo out)
        gemmT_mfma_k<<<dim3(8, NC/64, NB), 256, 0, stream>>>(adjTgc, (size_t)NC*NG, gT, gTlo,
                                                             (size_t)512*NG, NG, NC,
                                                             agg_bf, aggLo, nullptr);
        // clip_1 (3-pass hi/lo)
        run_fusion(c_cur, cLoC, agg_bf, aggLo, NC, l, 0, 3,
                   c_nxt, cLoN, nullptr, nullptr, cF);
        // clip_agg = attn0(q=gloss, kv=clip)
        attn_mfma_k<<<(NG/64)*32, 256, 0, stream>>>(bm_gc, NC/32, qs3, 0, ksh3, cmh3, ish3, 0,
                                                    WkT3, agg_bf, NG, NC);
        // gloss_1 (single pass; aLo still used for exact gate residual)
        run_fusion(g_cur, gLoC, agg_bf, nullptr, NG, l, 1, 1,
                   gA_bf, gALo, nullptr, nullptr, nullptr);
        // gloss_agg = attn1(q=question, kv=gloss)
        attn_mfma_k<<<(NQ/64)*32, 256, 0, stream>>>(bm_qg, NG/32, qs3, 1024, ksh3, cmh3, ish3, 1024,
                                                    WkT3, agg_bf, NQ, NG);
        // question_1 (single pass)
        run_fusion(q_cur, nullptr, agg_bf, nullptr, NQ, l, 2, 1,
                   q_nxt, nullptr, nullptr, nullptr, qF);
        // question_agg = attn2(q=gloss, kv=question)
        attn_mfma_k<<<(NG/64)*32, 256, 0, stream>>>(bm_gq, NQ/32, qs3, 1280, ksh3, cmh3, ish3, 2048,
                                                    WkT3, agg_bf, NG, NQ);
        // gloss_2 (3-pass; emit hi/lo + transposed hi/lo for next layer's gloss_same)
        run_fusion(gA_bf, gALo, agg_bf, nullptr, NG, l, 3, 3,
                   g_nxt, gLoN, (l == 0) ? gT : nullptr, (l == 0) ? gTlo : nullptr, gF);
    }
}